// Round 18
// baseline (146.953 us; speedup 1.0000x reference)
//
#include <hip/hip_runtime.h>
#include <hip/hip_bf16.h>
#include <math.h>

constexpr int Bn  = 16;
constexpr int Nn  = 1024;
constexpr int CIN = 3;
constexpr int En  = 64;
constexpr int Gn  = 16;
constexpr int PB  = En * Nn;      // 65536
constexpr int BEN = Bn * PB;      // 1,048,576
constexpr int NNc = Nn * Nn;      // 1,048,576

typedef __attribute__((ext_vector_type(8))) short bf16x8;
typedef __attribute__((ext_vector_type(4))) float f32x4;

__device__ inline ushort f2b(float f) {
  union { __hip_bfloat16 h; ushort u; } v;
  v.h = __float2bfloat16(f);
  return v.u;
}
__device__ inline float b2f(ushort u) {
  union { ushort u; __hip_bfloat16 h; } v;
  v.u = u;
  return __bfloat162float(v.h);
}

// ---------------------------------------------------------------------------
// MFMA bf16 GEMM core: 64x64 tile, 4 waves, BK=64.
// ASPLIT: A = [XAT | glEbf]. EPI: 4 C16 store; 6 den-only (atomics, no store).
// ---------------------------------------------------------------------------
template <int EPI, int BGEN, int ASPLIT>
__global__ __launch_bounds__(256) void mgemm_k(
    const ushort* __restrict__ A, const ushort* __restrict__ Bt,
    const ushort* __restrict__ A2,
    ushort* __restrict__ C16, ushort* __restrict__ C16b,
    const float* __restrict__ q1, const float* __restrict__ q2,
    const float* __restrict__ q4, float* __restrict__ dout,
    int K, int lda, int ldb, int ldc, long sA, long sB, long sC) {
  __shared__ ushort Al[5120];
  __shared__ ushort Bl[5120];
  int tid = threadIdx.x;
  int w = tid >> 6, l = tid & 63;
  int wm = (w >> 1) << 5, wn = (w & 1) << 5;
  int m0 = blockIdx.x << 6, n0 = blockIdx.y << 6, z = blockIdx.z;
  const ushort* Ab = A + (size_t)z * sA;
  const ushort* Bb = Bt + (size_t)z * sB;
  int r0 = tid >> 3, c0 = (tid & 7) << 3;
  int lo0 = (c0 >> 5) * 2560 + r0 * 40 + (c0 & 31);
  int lo1 = (c0 >> 5) * 2560 + (r0 + 32) * 40 + (c0 & 31);
  int fr = l & 15, fg = l >> 4;
  f32x4 acc[2][2] = {};

  int4 ra0, ra1, rb0, rb1;

  auto FETCH = [&](int k0) {
    if (ASPLIT) {
      const ushort* base = (k0 == 0) ? Ab : A2;
      ra0 = *(const int4*)(base + (size_t)(m0 + r0) * 64 + c0);
      ra1 = *(const int4*)(base + (size_t)(m0 + r0 + 32) * 64 + c0);
    } else {
      ra0 = *(const int4*)(Ab + (size_t)(m0 + r0) * lda + k0 + c0);
      ra1 = *(const int4*)(Ab + (size_t)(m0 + r0 + 32) * lda + k0 + c0);
    }
    rb0 = *(const int4*)(Bb + (size_t)(n0 + r0) * ldb + k0 + c0);
    rb1 = *(const int4*)(Bb + (size_t)(n0 + r0 + 32) * ldb + k0 + c0);
  };

  auto STORE = [&]() {
    *(int4*)&Al[lo0] = ra0;
    *(int4*)&Al[lo1] = ra1;
    *(int4*)&Bl[lo0] = rb0;
    *(int4*)&Bl[lo1] = rb1;
  };

  FETCH(0);
  for (int k0 = 0; k0 < K; k0 += 64) {
    __syncthreads();
    STORE();
    __syncthreads();
    if (k0 + 64 < K) FETCH(k0 + 64);
#pragma unroll
    for (int kk = 0; kk < 2; ++kk) {
      bf16x8 af[2], bfv[2];
#pragma unroll
      for (int i = 0; i < 2; ++i)
        af[i] = *(const bf16x8*)&Al[kk * 2560 + (wm + (i << 4) + fr) * 40 + (fg << 3)];
#pragma unroll
      for (int j = 0; j < 2; ++j)
        bfv[j] = *(const bf16x8*)&Bl[kk * 2560 + (wn + (j << 4) + fr) * 40 + (fg << 3)];
#pragma unroll
      for (int i = 0; i < 2; ++i)
#pragma unroll
        for (int j = 0; j < 2; ++j)
          acc[i][j] = __builtin_amdgcn_mfma_f32_16x16x32_bf16(
              af[i], bfv[j], acc[i][j], 0, 0, 0);
    }
  }

  int crb = (l >> 4) << 2, ccol = l & 15;
  if (EPI == 6) {
    // den-only: den[m] += sum_col exp(relu(v)); no C store
    float rp[8];
#pragma unroll
    for (int q = 0; q < 8; ++q) rp[q] = 0.f;
#pragma unroll
    for (int i = 0; i < 2; ++i)
#pragma unroll
      for (int j = 0; j < 2; ++j)
#pragma unroll
        for (int r = 0; r < 4; ++r) {
          float v = fmaxf(acc[i][j][r], 0.f);
          rp[i * 4 + r] += __expf(v);
        }
    __syncthreads();
    float* rs = (float*)Al;
    if (tid < 64) rs[tid] = 0.f;
    __syncthreads();
#pragma unroll
    for (int i = 0; i < 2; ++i)
#pragma unroll
      for (int r = 0; r < 4; ++r) {
        float p = rp[i * 4 + r];
#pragma unroll
        for (int msk = 1; msk < 16; msk <<= 1) p += __shfl_xor(p, msk);
        if ((l & 15) == 0) atomicAdd(&rs[wm + (i << 4) + crb + r], p);
      }
    __syncthreads();
    if (tid < 64) atomicAdd(&dout[((size_t)z << 10) + m0 + tid], rs[tid]);
  } else {
#pragma unroll
    for (int i = 0; i < 2; ++i)
#pragma unroll
      for (int j = 0; j < 2; ++j)
#pragma unroll
        for (int r = 0; r < 4; ++r) {
          int row = m0 + wm + (i << 4) + crb + r;
          int col = n0 + wn + (j << 4) + ccol;
          size_t off = (size_t)z * sC + (size_t)row * ldc + col;
          if (EPI == 4) C16[off] = f2b(acc[i][j][r]);
        }
  }
}

// ---------------------------------------------------------------------------
// pxa_k: split-K wave-groups + depth-2 pipeline.
// P generated in staging; out: XAbf [b][e][n] = relu(P@h), XAT [b][n][e].
// ---------------------------------------------------------------------------
__global__ __launch_bounds__(512) void pxa_k(
    const ushort* __restrict__ hT, const float* __restrict__ e1,
    const float* __restrict__ e2, const float* __restrict__ rsinv,
    ushort* __restrict__ XAbf, ushort* __restrict__ XAT) {
  __shared__ ushort Al[2][5120];
  __shared__ ushort Bl[2][5120];
  __shared__ float cmb[256 * 16];
  int tid = threadIdx.x;
  int grp = tid >> 8;
  int t = tid & 255;
  int w = t >> 6, l = t & 63;
  int wm = (w >> 1) << 5, wn = (w & 1) << 5;
  int n0 = blockIdx.x << 6, z = blockIdx.y;
  int kbase = grp << 9;
  const ushort* Ab = hT + (size_t)z * PB;
  int r0 = t >> 3, c0 = (t & 7) << 3;
  int lo0 = (c0 >> 5) * 2560 + r0 * 40 + (c0 & 31);
  int lo1 = (c0 >> 5) * 2560 + (r0 + 32) * 40 + (c0 & 31);
  int fr = l & 15, fg = l >> 4;
  f32x4 acc[2][2] = {};

  const float* e1b = e1 + (z << 10);
  const float* rsb = rsinv + (z << 10);
  float ei0 = e1b[n0 + r0], sc0 = rsb[n0 + r0];
  float ei1 = e1b[n0 + r0 + 32], sc1 = rsb[n0 + r0 + 32];

  int4 raA0, raA1, raB0, raB1;
  float fA[8], fB[8];

  auto FETCHA = [&](int k0) {
    raA0 = *(const int4*)(Ab + (size_t)r0 * 1024 + k0 + c0);
    raA1 = *(const int4*)(Ab + (size_t)(r0 + 32) * 1024 + k0 + c0);
    const float* e2b = e2 + (z << 10) + k0 + c0;
    *(float4*)&fA[0] = *(const float4*)(e2b);
    *(float4*)&fA[4] = *(const float4*)(e2b + 4);
  };
  auto FETCHB = [&](int k0) {
    raB0 = *(const int4*)(Ab + (size_t)r0 * 1024 + k0 + c0);
    raB1 = *(const int4*)(Ab + (size_t)(r0 + 32) * 1024 + k0 + c0);
    const float* e2b = e2 + (z << 10) + k0 + c0;
    *(float4*)&fB[0] = *(const float4*)(e2b);
    *(float4*)&fB[4] = *(const float4*)(e2b + 4);
  };
  auto STOREA = [&]() {
    *(int4*)&Al[grp][lo0] = raA0;
    *(int4*)&Al[grp][lo1] = raA1;
    ushort o0[8], o1[8];
#pragma unroll
    for (int q = 0; q < 8; ++q) {
      float z0 = ei0 + fA[q];
      z0 = z0 >= 0.f ? z0 : 0.01f * z0;
      o0[q] = f2b(__expf(z0) * sc0);
      float z1 = ei1 + fA[q];
      z1 = z1 >= 0.f ? z1 : 0.01f * z1;
      o1[q] = f2b(__expf(z1) * sc1);
    }
    *(int4*)&Bl[grp][lo0] = *(int4*)o0;
    *(int4*)&Bl[grp][lo1] = *(int4*)o1;
  };
  auto STOREB = [&]() {
    *(int4*)&Al[grp][lo0] = raB0;
    *(int4*)&Al[grp][lo1] = raB1;
    ushort o0[8], o1[8];
#pragma unroll
    for (int q = 0; q < 8; ++q) {
      float z0 = ei0 + fB[q];
      z0 = z0 >= 0.f ? z0 : 0.01f * z0;
      o0[q] = f2b(__expf(z0) * sc0);
      float z1 = ei1 + fB[q];
      z1 = z1 >= 0.f ? z1 : 0.01f * z1;
      o1[q] = f2b(__expf(z1) * sc1);
    }
    *(int4*)&Bl[grp][lo0] = *(int4*)o0;
    *(int4*)&Bl[grp][lo1] = *(int4*)o1;
  };
  auto MFMAS = [&]() {
#pragma unroll
    for (int kk = 0; kk < 2; ++kk) {
      bf16x8 af[2], bfv[2];
#pragma unroll
      for (int i = 0; i < 2; ++i)
        af[i] = *(const bf16x8*)&Al[grp][kk * 2560 + (wm + (i << 4) + fr) * 40 + (fg << 3)];
#pragma unroll
      for (int j = 0; j < 2; ++j)
        bfv[j] = *(const bf16x8*)&Bl[grp][kk * 2560 + (wn + (j << 4) + fr) * 40 + (fg << 3)];
#pragma unroll
      for (int i = 0; i < 2; ++i)
#pragma unroll
        for (int j = 0; j < 2; ++j)
          acc[i][j] = __builtin_amdgcn_mfma_f32_16x16x32_bf16(
              af[i], bfv[j], acc[i][j], 0, 0, 0);
    }
  };

  FETCHA(kbase);
  FETCHB(kbase + 64);
  for (int ks = 0; ks < 8; ks += 2) {
    __syncthreads();
    STOREA();
    __syncthreads();
    if (ks + 2 < 8) FETCHA(kbase + ((ks + 2) << 6));
    MFMAS();
    __syncthreads();
    STOREB();
    __syncthreads();
    if (ks + 3 < 8) FETCHB(kbase + ((ks + 3) << 6));
    MFMAS();
  }

  __syncthreads();
  if (grp == 1) {
    float* d = cmb + t * 16;
#pragma unroll
    for (int i = 0; i < 2; ++i)
#pragma unroll
      for (int j = 0; j < 2; ++j)
#pragma unroll
        for (int r = 0; r < 4; ++r) d[((i << 1) + j) * 4 + r] = acc[i][j][r];
  }
  __syncthreads();
  if (grp == 1) return;
  const float* s = cmb + t * 16;
#pragma unroll
  for (int i = 0; i < 2; ++i)
#pragma unroll
    for (int j = 0; j < 2; ++j)
#pragma unroll
      for (int r = 0; r < 4; ++r) acc[i][j][r] += s[((i << 1) + j) * 4 + r];

  int crb = (l >> 4) << 2, ccol = l & 15;
#pragma unroll
  for (int i = 0; i < 2; ++i)
#pragma unroll
    for (int j = 0; j < 2; ++j)
#pragma unroll
      for (int r = 0; r < 4; ++r) {
        int row = wm + (i << 4) + crb + r;        // e index
        int col = n0 + wn + (j << 4) + ccol;      // node index
        float v = fmaxf(acc[i][j][r], 0.f);
        XAbf[(size_t)z * PB + (size_t)row * 1024 + col] = f2b(v);
        XAT[(size_t)z * PB + (size_t)col * 64 + row] = f2b(v);
      }
}

// ---------------------------------------------------------------------------
// gg_k (depth-2), grid (16,16,2).
// z=0: H02 = H0 @ emb2_w^T + emb2_b (fp32); z=1: g12T = g2t @ g1t (bf16).
// ---------------------------------------------------------------------------
__global__ __launch_bounds__(256) void gg_k(
    const ushort* __restrict__ H0bf, const ushort* __restrict__ e2wbf,
    const float* __restrict__ emb2b, float* __restrict__ H02,
    const ushort* __restrict__ g2t, const ushort* __restrict__ g1t,
    ushort* __restrict__ g12T) {
  __shared__ ushort Al[5120];
  __shared__ ushort Bl[5120];
  int tid = threadIdx.x;
  int w = tid >> 6, l = tid & 63;
  int wm = (w >> 1) << 5, wn = (w & 1) << 5;
  int m0 = blockIdx.x << 6, n0 = blockIdx.y << 6;
  int job = blockIdx.z;
  const ushort* Ab = job ? g2t : H0bf;
  int r0 = tid >> 3, c0 = (tid & 7) << 3;
  int lo0 = (c0 >> 5) * 2560 + r0 * 40 + (c0 & 31);
  int lo1 = (c0 >> 5) * 2560 + (r0 + 32) * 40 + (c0 & 31);
  int fr = l & 15, fg = l >> 4;
  f32x4 acc[2][2] = {};
  int4 raA0, raA1, rbA0, rbA1;
  int4 raB0, raB1, rbB0, rbB1;

  auto FETCHA = [&](int k0) {
    raA0 = *(const int4*)(Ab + (size_t)(m0 + r0) * 1024 + k0 + c0);
    raA1 = *(const int4*)(Ab + (size_t)(m0 + r0 + 32) * 1024 + k0 + c0);
    if (job) {
      rbA0 = *(const int4*)(g1t + (size_t)(k0 + r0) * 1024 + n0 + c0);
      rbA1 = *(const int4*)(g1t + (size_t)(k0 + r0 + 32) * 1024 + n0 + c0);
    } else {
      rbA0 = *(const int4*)(e2wbf + (size_t)(n0 + r0) * 1024 + k0 + c0);
      rbA1 = *(const int4*)(e2wbf + (size_t)(n0 + r0 + 32) * 1024 + k0 + c0);
    }
  };
  auto FETCHB = [&](int k0) {
    raB0 = *(const int4*)(Ab + (size_t)(m0 + r0) * 1024 + k0 + c0);
    raB1 = *(const int4*)(Ab + (size_t)(m0 + r0 + 32) * 1024 + k0 + c0);
    if (job) {
      rbB0 = *(const int4*)(g1t + (size_t)(k0 + r0) * 1024 + n0 + c0);
      rbB1 = *(const int4*)(g1t + (size_t)(k0 + r0 + 32) * 1024 + n0 + c0);
    } else {
      rbB0 = *(const int4*)(e2wbf + (size_t)(n0 + r0) * 1024 + k0 + c0);
      rbB1 = *(const int4*)(e2wbf + (size_t)(n0 + r0 + 32) * 1024 + k0 + c0);
    }
  };
  auto STOREA = [&]() {
    *(int4*)&Al[lo0] = raA0;
    *(int4*)&Al[lo1] = raA1;
    if (job) {
      const ushort* p0 = (const ushort*)&rbA0;
      const ushort* p1 = (const ushort*)&rbA1;
#pragma unroll
      for (int q = 0; q < 8; ++q) {
        Bl[(c0 + q) * 40 + r0] = p0[q];
        Bl[2560 + (c0 + q) * 40 + r0] = p1[q];
      }
    } else {
      *(int4*)&Bl[lo0] = rbA0;
      *(int4*)&Bl[lo1] = rbA1;
    }
  };
  auto STOREB = [&]() {
    *(int4*)&Al[lo0] = raB0;
    *(int4*)&Al[lo1] = raB1;
    if (job) {
      const ushort* p0 = (const ushort*)&rbB0;
      const ushort* p1 = (const ushort*)&rbB1;
#pragma unroll
      for (int q = 0; q < 8; ++q) {
        Bl[(c0 + q) * 40 + r0] = p0[q];
        Bl[2560 + (c0 + q) * 40 + r0] = p1[q];
      }
    } else {
      *(int4*)&Bl[lo0] = rbB0;
      *(int4*)&Bl[lo1] = rbB1;
    }
  };
  auto MFMAS = [&]() {
#pragma unroll
    for (int kk = 0; kk < 2; ++kk) {
      bf16x8 af[2], bfv[2];
#pragma unroll
      for (int i = 0; i < 2; ++i)
        af[i] = *(const bf16x8*)&Al[kk * 2560 + (wm + (i << 4) + fr) * 40 + (fg << 3)];
#pragma unroll
      for (int j = 0; j < 2; ++j)
        bfv[j] = *(const bf16x8*)&Bl[kk * 2560 + (wn + (j << 4) + fr) * 40 + (fg << 3)];
#pragma unroll
      for (int i = 0; i < 2; ++i)
#pragma unroll
        for (int j = 0; j < 2; ++j)
          acc[i][j] = __builtin_amdgcn_mfma_f32_16x16x32_bf16(
              af[i], bfv[j], acc[i][j], 0, 0, 0);
    }
  };

  FETCHA(0);
  FETCHB(64);
  for (int ks = 0; ks < 16; ks += 2) {
    __syncthreads();
    STOREA();
    __syncthreads();
    if (ks + 2 < 16) FETCHA((ks + 2) << 6);
    MFMAS();
    __syncthreads();
    STOREB();
    __syncthreads();
    if (ks + 3 < 16) FETCHB((ks + 3) << 6);
    MFMAS();
  }

  int crb = (l >> 4) << 2, ccol = l & 15;
#pragma unroll
  for (int i = 0; i < 2; ++i)
#pragma unroll
    for (int j = 0; j < 2; ++j)
#pragma unroll
      for (int r = 0; r < 4; ++r) {
        int row = m0 + wm + (i << 4) + crb + r;
        int col = n0 + wn + (j << 4) + ccol;
        float v = acc[i][j][r];
        if (job) g12T[(size_t)row * 1024 + col] = f2b(v);
        else H02[(size_t)row * 1024 + col] = v + emb2b[col];
      }
}

// ---------------------------------------------------------------------------
// fuw_k (R18): flash-style u/w + ymix. ST tiles regenerated from ge (L2)
// instead of reading the 32MB E matrix from HBM.
// Per K-step: stage geK/XA/g12 (L2) -> QK MFMA -> exp*rcp(den) -> pack to
// A-layout LDS -> u/w MFMA. Then colS, UW, phase C (y1/y2 + rank1 + LN).
// grid (16 m-tiles, 16 batches), 256 threads.
// ---------------------------------------------------------------------------
__global__ __launch_bounds__(256) void fuw_k(
    const ushort* __restrict__ ge, const float* __restrict__ den,
    const ushort* __restrict__ g12T, const ushort* __restrict__ XAbf,
    const ushort* __restrict__ XAT, const ushort* __restrict__ Acat,
    const float* __restrict__ b2, const float* __restrict__ lb2,
    const float* __restrict__ c2, const float* __restrict__ c12,
    ushort* __restrict__ y1, ushort* __restrict__ y2,
    float* __restrict__ part) {
  __shared__ ushort geM[4 * 2560];   // [4 c-chunks][64][40] (m-tile ge rows)
  __shared__ ushort geK[4 * 2560];   // per-step k-tile ge rows
  __shared__ ushort Au[2 * 2560];    // regenerated ST tile (A layout)
  __shared__ ushort Ag[2 * 2560];    // g12 tile
  __shared__ ushort Bx[2 * 2560];    // XA tile
  __shared__ ushort UW[64 * 132];
  __shared__ float rden[1024];
  __shared__ float colS[64];
  int tid = threadIdx.x;
  int w = tid >> 6, l = tid & 63;
  int wm = (w >> 1) << 5, wn = (w & 1) << 5;
  int m0 = blockIdx.x << 6, z = blockIdx.y;
  const ushort* geb = ge + (size_t)z * Nn * 128;
  const ushort* Bb = XAbf + (size_t)z * PB;
  int r0 = tid >> 3, c0 = (tid & 7) << 3;
  int lo0 = (c0 >> 5) * 2560 + r0 * 40 + (c0 & 31);
  int lo1 = (c0 >> 5) * 2560 + (r0 + 32) * 40 + (c0 & 31);
  int fr = l & 15, fg = l >> 4;
  int crb = (l >> 4) << 2, ccol = l & 15;

  // preload rcp(den) + zero colS
  {
    float4 d4 = *(const float4*)(den + (z << 10) + (tid << 2));
    rden[(tid << 2) + 0] = __builtin_amdgcn_rcpf(d4.x);
    rden[(tid << 2) + 1] = __builtin_amdgcn_rcpf(d4.y);
    rden[(tid << 2) + 2] = __builtin_amdgcn_rcpf(d4.z);
    rden[(tid << 2) + 3] = __builtin_amdgcn_rcpf(d4.w);
  }
  if (tid < 64) colS[tid] = 0.f;

  // stage geM once: rows m0+r0 / m0+r0+32, c-halves h = 0,1
#pragma unroll
  for (int h = 0; h < 2; ++h) {
    int ch = (h << 1) + (c0 >> 5);
    *(int4*)&geM[ch * 2560 + r0 * 40 + (c0 & 31)] =
        *(const int4*)(geb + (size_t)(m0 + r0) * 128 + h * 64 + c0);
    *(int4*)&geM[ch * 2560 + (r0 + 32) * 40 + (c0 & 31)] =
        *(const int4*)(geb + (size_t)(m0 + r0 + 32) * 128 + h * 64 + c0);
  }

  f32x4 au[2][2] = {};
  f32x4 aw[2][2] = {};
  float csr[8];
#pragma unroll
  for (int q = 0; q < 8; ++q) csr[q] = 0.f;

  int4 gk0, gk1, gk2, gk3, bx0, bx1, ag0, ag1;
  auto FETCH = [&](int k0) {
    gk0 = *(const int4*)(geb + (size_t)(k0 + r0) * 128 + c0);
    gk1 = *(const int4*)(geb + (size_t)(k0 + r0 + 32) * 128 + c0);
    gk2 = *(const int4*)(geb + (size_t)(k0 + r0) * 128 + 64 + c0);
    gk3 = *(const int4*)(geb + (size_t)(k0 + r0 + 32) * 128 + 64 + c0);
    bx0 = *(const int4*)(Bb + (size_t)r0 * 1024 + k0 + c0);
    bx1 = *(const int4*)(Bb + (size_t)(r0 + 32) * 1024 + k0 + c0);
    ag0 = *(const int4*)(g12T + (size_t)(m0 + r0) * 1024 + k0 + c0);
    ag1 = *(const int4*)(g12T + (size_t)(m0 + r0 + 32) * 1024 + k0 + c0);
  };
  auto STORE = [&]() {
    int ch = c0 >> 5;
    *(int4*)&geK[ch * 2560 + r0 * 40 + (c0 & 31)] = gk0;
    *(int4*)&geK[ch * 2560 + (r0 + 32) * 40 + (c0 & 31)] = gk1;
    *(int4*)&geK[(2 + ch) * 2560 + r0 * 40 + (c0 & 31)] = gk2;
    *(int4*)&geK[(2 + ch) * 2560 + (r0 + 32) * 40 + (c0 & 31)] = gk3;
    *(int4*)&Bx[lo0] = bx0;
    *(int4*)&Bx[lo1] = bx1;
    *(int4*)&Ag[lo0] = ag0;
    *(int4*)&Ag[lo1] = ag1;
  };

  FETCH(0);
  for (int k0 = 0; k0 < 1024; k0 += 64) {
    __syncthreads();
    STORE();
    __syncthreads();
    if (k0 + 64 < 1024) FETCH(k0 + 64);
    // QK: sym tile [m][k] = geM @ geK^T over c=128 (4 chunks of 32)
    f32x4 as[2][2] = {};
#pragma unroll
    for (int kk = 0; kk < 4; ++kk) {
      bf16x8 am[2], bk[2];
#pragma unroll
      for (int i = 0; i < 2; ++i)
        am[i] = *(const bf16x8*)&geM[kk * 2560 + (wm + (i << 4) + fr) * 40 + (fg << 3)];
#pragma unroll
      for (int j = 0; j < 2; ++j)
        bk[j] = *(const bf16x8*)&geK[kk * 2560 + (wn + (j << 4) + fr) * 40 + (fg << 3)];
#pragma unroll
      for (int i = 0; i < 2; ++i)
#pragma unroll
        for (int j = 0; j < 2; ++j)
          as[i][j] = __builtin_amdgcn_mfma_f32_16x16x32_bf16(
              am[i], bk[j], as[i][j], 0, 0, 0);
    }
    // exp * rcp(den) -> pack into Au (A layout); colS partials
#pragma unroll
    for (int i = 0; i < 2; ++i)
#pragma unroll
      for (int j = 0; j < 2; ++j)
#pragma unroll
        for (int r = 0; r < 4; ++r) {
          int row = wm + (i << 4) + crb + r;
          int col = wn + (j << 4) + ccol;
          float v = fmaxf(as[i][j][r], 0.f);
          float st = __expf(v) * rden[k0 + col];
          csr[i * 4 + r] += st;
          Au[(col >> 5) * 2560 + row * 40 + (col & 31)] = f2b(st);
        }
    __syncthreads();
    // u/w MFMA over this 64-k step
#pragma unroll
    for (int kk = 0; kk < 2; ++kk) {
      bf16x8 fu[2], fw[2], fb[2];
#pragma unroll
      for (int i = 0; i < 2; ++i) {
        int off = kk * 2560 + (wm + (i << 4) + fr) * 40 + (fg << 3);
        fu[i] = *(const bf16x8*)&Au[off];
        fw[i] = *(const bf16x8*)&Ag[off];
      }
#pragma unroll
      for (int j = 0; j < 2; ++j)
        fb[j] = *(const bf16x8*)&Bx[kk * 2560 + (wn + (j << 4) + fr) * 40 + (fg << 3)];
#pragma unroll
      for (int i = 0; i < 2; ++i)
#pragma unroll
        for (int j = 0; j < 2; ++j) {
          au[i][j] = __builtin_amdgcn_mfma_f32_16x16x32_bf16(
              fu[i], fb[j], au[i][j], 0, 0, 0);
          aw[i][j] = __builtin_amdgcn_mfma_f32_16x16x32_bf16(
              fw[i], fb[j], aw[i][j], 0, 0, 0);
        }
    }
  }

  // colS: reduce across the 16 col-lanes, then LDS atomics (2 waves/row set)
#pragma unroll
  for (int q = 0; q < 8; ++q) {
#pragma unroll
    for (int msk = 1; msk < 16; msk <<= 1) csr[q] += __shfl_xor(csr[q], msk);
  }
  if ((l & 15) == 0) {
#pragma unroll
    for (int i = 0; i < 2; ++i)
#pragma unroll
      for (int r = 0; r < 4; ++r)
        atomicAdd(&colS[wm + (i << 4) + crb + r], csr[i * 4 + r]);
  }
  __syncthreads();

  // UW fill: u (+ xa^T aux) and w (B-operand layout for phase C)
#pragma unroll
  for (int i = 0; i < 2; ++i)
#pragma unroll
    for (int j = 0; j < 2; ++j)
#pragma unroll
      for (int r = 0; r < 4; ++r) {
        int node = wm + (i << 4) + crb + r;
        int e = wn + (j << 4) + ccol;
        float uv = au[i][j][r] +
                   b2f(XAT[(size_t)z * PB + (size_t)(m0 + node) * 64 + e]);
        UW[node * 132 + e] = f2b(uv);
        UW[node * 132 + 64 + e] = f2b(aw[i][j][r]);
      }
  __syncthreads();

  // phase C: y = Acat @ [u;w] (K=128). waves 0,1 -> y1; 2,3 -> y2.
  int half = w >> 1;
  int mrow = (w & 1) << 5;
  const ushort* Ac = Acat + half * 8192;
  bf16x8 af[2][4];
#pragma unroll
  for (int i = 0; i < 2; ++i)
#pragma unroll
    for (int s = 0; s < 4; ++s)
      af[i][s] = *(const bf16x8*)&Ac[(mrow + i * 16 + fr) * 128 + s * 32 + fg * 8];
  f32x4 acc[2][4] = {};
#pragma unroll
  for (int s = 0; s < 4; ++s) {
    bf16x8 bv[4];
#pragma unroll
    for (int j = 0; j < 4; ++j)
      bv[j] = *(const bf16x8*)&UW[(j * 16 + fr) * 132 + s * 32 + fg * 8];
#pragma unroll
    for (int i = 0; i < 2; ++i)
#pragma unroll
      for (int j = 0; j < 4; ++j)
        acc[i][j] = __builtin_amdgcn_mfma_f32_16x16x32_bf16(
            af[i][s], bv[j], acc[i][j], 0, 0, 0);
  }
  ushort* Y = half ? y2 : y1;
  float ysum = 0.f, yss = 0.f;
#pragma unroll
  for (int i = 0; i < 2; ++i)
#pragma unroll
    for (int j = 0; j < 4; ++j) {
      int node = (j << 4) + ccol;
      float rk = 0.f, r12 = 0.f;
      if (half) {
        rk = 1.0f + colS[node] + c2[m0 + node];
        r12 = c12[m0 + node];
      }
#pragma unroll
      for (int r = 0; r < 4; ++r) {
        int row = mrow + (i << 4) + crb + r;
        float v = acc[i][j][r];
        if (half) v += b2[row] * rk + lb2[row] * r12;
        Y[(size_t)z * PB + (size_t)row * 1024 + m0 + node] = f2b(v);
        ysum += v;
        yss = fmaf(v, v, yss);
      }
    }
#pragma unroll
  for (int msk = 1; msk < 64; msk <<= 1) {
    ysum += __shfl_xor(ysum, msk);
    yss += __shfl_xor(yss, msk);
  }
  if (l == 0) {
    atomicAdd(&part[half * 32 + z * 2], ysum);
    atomicAdd(&part[half * 32 + z * 2 + 1], yss);
  }
}

// ---------------------------------------------------------------------------
// prep0_k: [0,2048) lap rowsum; [2048,2402) Acat/lb2/part0/glE/den0;
// [2402,10658) weight casts + embedding.
// ---------------------------------------------------------------------------
__global__ __launch_bounds__(256) void prep0_k(
    const float* __restrict__ graph, float* __restrict__ dd,
    const float* __restrict__ L1, const float* __restrict__ L2,
    const float* __restrict__ b2, float* __restrict__ lb2,
    ushort* __restrict__ Acat, const float* __restrict__ GL,
    const float* __restrict__ GLlin_w, ushort* __restrict__ glEbf,
    const float* __restrict__ emb2w, const float* __restrict__ w2,
    ushort* __restrict__ e2wbf, ushort* __restrict__ w2bf,
    const float* __restrict__ x, const float* __restrict__ emb_w,
    const float* __restrict__ emb_b, ushort* __restrict__ H0,
    float* __restrict__ part, float* __restrict__ den) {
  int blk = blockIdx.x, tid = threadIdx.x;
  if (blk < 2048) {
    const float* row = graph + (size_t)blk * Nn;
    float s = 0.0f;
    for (int j = tid; j < Nn; j += 256) s += row[j];
    __shared__ float red[256];
    red[tid] = s;
    __syncthreads();
    for (int st = 128; st > 0; st >>= 1) {
      if (tid < st) red[tid] += red[tid + st];
      __syncthreads();
    }
    if (tid == 0) {
      float t = red[0] + 1.0f;
      dd[blk] = (t > 0.0f) ? rsqrtf(t) : 0.0f;
    }
  } else if (blk < 2402) {
    int pblk = blk - 2048;
    if (pblk < 32) {
      int mat = pblk >> 4;
      int o = ((pblk & 15) << 8) + tid;
      int e = o >> 6, c = o & 63;
      const float* L = mat ? L2 : L1;
      float s = 0.f;
#pragma unroll
      for (int t = 0; t < 64; ++t) s = fmaf(L[e * 64 + t], L[t * 64 + c], s);
      Acat[mat * 8192 + e * 128 + 64 + c] = f2b(s);
    } else if (pblk == 32) {
      for (int t = tid; t < 8192; t += 256) {
        int w = t >> 12, rem = t & 4095, m = rem >> 6, k = rem & 63;
        Acat[w * 8192 + m * 128 + k] = f2b((w ? L2 : L1)[m * 64 + k]);
      }
    } else if (pblk == 33) {
      if (tid < 64) {
        float s = 0.f;
#pragma unroll
        for (int c = 0; c < 64; ++c) s = fmaf(L2[tid * 64 + c], b2[c], s);
        lb2[tid] = s;
      } else if (tid < 128) {
        part[tid - 64] = 0.f;
      }
    } else if (pblk < 290) {
      int idx = (pblk - 34) * 256 + tid;  // < 65536
      int n = idx >> 6, e = idx & 63;
      float s = 0.0f;
#pragma unroll
      for (int g = 0; g < Gn; ++g)
        s = fmaf(GL[n * Gn + g], GLlin_w[e * Gn + g], s);
      glEbf[idx] = f2b(s);
    } else {
      int idx = (pblk - 290) * 256 + tid;  // < 16384
      den[idx] = 0.f;
    }
  } else {
    int cblk = blk - 2402;
    if (cblk < 4160) {
      int idx = cblk * 256 + tid;
      if (idx < NNc) e2wbf[idx] = f2b(emb2w[idx]);
      else if (idx < NNc + 16384) w2bf[idx - NNc] = f2b(w2[idx - NNc]);
    } else {
      int idx = (cblk - 4160) * 256 + tid;  // < BEN
      int b = idx >> 16, r = idx & 65535, e = r >> 10, n = r & 1023;
      const float* xb = x + (size_t)b * (CIN * Nn);
      float s = emb_b[e] + emb_w[e * 3 + 0] * xb[n] +
                emb_w[e * 3 + 1] * xb[Nn + n] +
                emb_w[e * 3 + 2] * xb[2 * Nn + n];
      s = s >= 0.0f ? s : 0.01f * s;
      H0[idx] = f2b(s);
    }
  }
}

// One pass over graph row (g,m): write g_t row m (bf16) + c_g[m].
__global__ __launch_bounds__(256) void lap_fused_k(
    const float* __restrict__ graph, const float* __restrict__ dd,
    ushort* __restrict__ g1t, ushort* __restrict__ g2t,
    float* __restrict__ c1, float* __restrict__ c2) {
  int gi = blockIdx.x;
  int g = gi >> 10, m = gi & 1023;
  const float* grow = graph + (size_t)gi * Nn;
  const float* ddg = dd + (g << 10);
  float ddm = ddg[m];
  ushort* gt = (g ? g2t : g1t) + (size_t)m * Nn;
  int tid = threadIdx.x;
  float s = 0.0f;
  for (int n = tid; n < Nn; n += 256) {
    float t = ddg[n] * grow[n];
    s += t;
    float v = t * ddm + (n == m ? ddm * ddm : 0.f);
    gt[n] = f2b(v);
  }
  __shared__ float red[256];
  red[tid] = s;
  __syncthreads();
  for (int st = 128; st > 0; st >>= 1) {
    if (tid < st) red[tid] += red[tid + st];
    __syncthreads();
  }
  if (tid == 0) (g ? c2 : c1)[m] = ddm * (red[0] + ddm);
}

// out[m] = lap-column action with vector vin (for c12)
__global__ __launch_bounds__(256) void lap_vec_k(
    const float* __restrict__ graph, const float* __restrict__ dd,
    const float* __restrict__ vin, float* __restrict__ out, int g) {
  int m = blockIdx.x;
  int tid = threadIdx.x;
  const float* grow = graph + (size_t)g * NNc + (size_t)m * Nn;
  const float* ddg = dd + (g << 10);
  float s = 0.0f;
  for (int n = tid; n < Nn; n += 256) s += ddg[n] * grow[n] * vin[n];
  __shared__ float red[256];
  red[tid] = s;
  __syncthreads();
  for (int st = 128; st > 0; st >>= 1) {
    if (tid < st) red[tid] += red[tid + st];
    __syncthreads();
  }
  if (tid == 0) out[m] = ddg[m] * (red[0] + ddg[m] * vin[m]);
}

// hT = attW-mix of H02; e1/e2 dots with att_a
__global__ __launch_bounds__(256) void hmix_k(
    const float* __restrict__ H02, const float* __restrict__ attW,
    const float* __restrict__ atta, ushort* __restrict__ hT,
    float* __restrict__ e1, float* __restrict__ e2) {
  __shared__ float Hs[64][65];
  __shared__ float pr1[4][64];
  __shared__ float pr2[4][64];
  int tid = threadIdx.x;
  int blk = blockIdx.x;
  int b = blk >> 4, n0 = (blk & 15) << 6;
  for (int t = tid; t < 4096; t += 256) {
    int e = t >> 6, n = t & 63;
    Hs[e][n] = H02[(size_t)(b * 64 + e) * 1024 + n0 + n];
  }
  __syncthreads();
  int n = tid & 63, epg = tid >> 6;
  float h[16];
#pragma unroll
  for (int i = 0; i < 16; ++i) h[i] = 0.f;
  for (int e = 0; e < 64; ++e) {
    float xv = Hs[e][n];
#pragma unroll
    for (int i = 0; i < 16; ++i)
      h[i] = fmaf(xv, attW[e * 64 + epg * 16 + i], h[i]);
  }
  float s1 = 0.f, s2 = 0.f;
#pragma unroll
  for (int i = 0; i < 16; ++i) {
    int ep = epg * 16 + i;
    hT[(size_t)(b * 64 + ep) * 1024 + n0 + n] = f2b(h[i]);
    s1 = fmaf(h[i], atta[ep], s1);
    s2 = fmaf(h[i], atta[64 + ep], s2);
  }
  pr1[epg][n] = s1;
  pr2[epg][n] = s2;
  __syncthreads();
  if (epg == 0) {
    e1[(b << 10) + n0 + n] = pr1[0][n] + pr1[1][n] + pr1[2][n] + pr1[3][n];
    e2[(b << 10) + n0 + n] = pr2[0][n] + pr2[1][n] + pr2[2][n] + pr2[3][n];
  }
}

// rsinv[i] = 1 / sum_j exp(lrelu(e1_i + e2_j))   (no-max softmax)
__global__ __launch_bounds__(256) void att_rowstats_k(
    const float* __restrict__ e1, const float* __restrict__ e2,
    float* __restrict__ rsinv) {
  int row = blockIdx.x;
  int b = row >> 10;
  const float* e2b = e2 + (b << 10);
  float a = e1[row];
  int tid = threadIdx.x;
  float sm = 0.0f;
#pragma unroll
  for (int l = 0; l < 4; ++l) {
    float v = a + e2b[tid + (l << 8)];
    v = v >= 0.0f ? v : 0.01f * v;
    sm += __expf(v);
  }
  __shared__ float red[256];
  red[tid] = sm;
  __syncthreads();
  for (int s = 128; s > 0; s >>= 1) {
    if (tid < s) red[tid] += red[tid + s];
    __syncthreads();
  }
  if (tid == 0) rsinv[row] = 1.0f / red[0];
}

// final: LN finish + affine + gelu + cell update (y1/y2 bf16)
__global__ __launch_bounds__(256) void final_k(
    const ushort* __restrict__ y1, const ushort* __restrict__ y2,
    const ushort* __restrict__ xabf, const float* __restrict__ ct,
    const float* __restrict__ ln_w, const float* __restrict__ ln_b,
    const float* __restrict__ part, float* __restrict__ out) {
  __shared__ float st[4];
  int idx = blockIdx.x * 256 + threadIdx.x;
  int b = idx >> 16, r = idx & 65535;
  if (threadIdx.x < 2) {
    int wq = threadIdx.x;
    float s = part[wq * 32 + b * 2];
    float ss = part[wq * 32 + b * 2 + 1];
    float mean = s * (1.0f / PB);
    float var = fmaxf(ss * (1.0f / PB) - mean * mean, 0.0f);
    st[wq * 2] = mean;
    st[wq * 2 + 1] = rsqrtf(var + 1e-5f);
  }
  __syncthreads();
  float m1 = st[0], s1 = st[1], m2 = st[2], s2 = st[3];
  float w = ln_w[r], bb = ln_b[r];
  float xn = (b2f(y1[idx]) - m1) * s1 * w + bb;
  float yg = (b2f(y2[idx]) - m2) * s2 * w + bb;
  float g = 0.5f * yg * (1.0f + erff(yg * 0.70710678118654752f));
  float c = ct[idx];
  float cn = xn + g * (c - xn);
  float el = cn > 0.0f ? cn : expm1f(cn);
  float xv = b2f(xabf[idx]);
  out[idx] = xv + g * (el - xv);
  out[BEN + idx] = cn;
}

extern "C" void kernel_launch(void* const* d_in, const int* in_sizes, int n_in,
                              void* d_out, int out_size, void* d_ws,
                              size_t ws_size, hipStream_t stream) {
  const float* x       = (const float*)d_in[0];
  const float* ct      = (const float*)d_in[1];
  const float* graph   = (const float*)d_in[2];
  const float* emb_w   = (const float*)d_in[3];
  const float* emb_b   = (const float*)d_in[4];
  const float* emb2_w  = (const float*)d_in[5];
  const float* emb2_b  = (const float*)d_in[6];
  const float* att_W   = (const float*)d_in[7];
  const float* att_a   = (const float*)d_in[8];
  const float* lin1_w  = (const float*)d_in[10];
  const float* lin2_w  = (const float*)d_in[11];
  const float* lin2_b  = (const float*)d_in[12];
  const float* ln_w    = (const float*)d_in[13];
  const float* ln_b    = (const float*)d_in[14];
  const float* GL      = (const float*)d_in[15];
  const float* GLlin_w = (const float*)d_in[16];
  const float* GLlin2_w= (const float*)d_in[17];
  float* out = (float*)d_out;

  ushort* U = (ushort*)d_ws;
  float* F = (float*)d_ws;
  const int M1U = 1048576;
  ushort* symP  = U + 0;            // (unused in R18)
  ushort* H0bf  = U + 16 * M1U;
  ushort* e2wbf = U + 17 * M1U;
  ushort* g1tbf = U + 18 * M1U;
  ushort* g2tbf = U + 19 * M1U;
  ushort* hTbf  = U + 20 * M1U;
  ushort* XAbf  = U + 21 * M1U;     // [b][e][n]
  ushort* XAT   = U + 22 * M1U;     // [b][n][e]
  ushort* g12T  = U + 23 * M1U;     // [n][k]
  ushort* gebf  = U + 24 * M1U;     // 2M  [b][n][128]
  ushort* y1b   = U + 26 * M1U;     // [b][e][n] bf16
  ushort* y2b   = U + 27 * M1U;
  ushort* w2bf  = U + 28 * M1U;     // 16K
  ushort* Acat  = U + 28 * M1U + 16384;
  ushort* glEbf = U + 28 * M1U + 32768;  // 64K
  // ushort region ends at 29,458,432 ushorts = 14,729,216 floats
  float* H02  = F + 14729216;
  float* SM   = F + 15777792;
  float* e1    = SM;
  float* e2    = SM + 16384;
  float* rsinv = SM + 32768;
  float* dd    = SM + 49152;   // 2048
  float* c1    = SM + 51200;
  float* c2    = SM + 52224;
  float* c12   = SM + 53248;
  float* lb2   = SM + 54272;   // 64 (pad)
  float* den   = SM + 54400;   // 16384
  float* part  = SM + 70784;   // 64

  // merged prep: lap rowsum | Acat/lb2/part0/glE/den0 | casts + embedding
  prep0_k<<<10658, 256, 0, stream>>>(
      graph, dd, lin1_w, lin2_w, lin2_b, lb2, Acat, GL, GLlin_w, glEbf,
      emb2_w, GLlin2_w, e2wbf, w2bf, x, emb_w, emb_b, H0bf, part, den);
  lap_fused_k<<<2048, 256, 0, stream>>>(graph, dd, g1tbf, g2tbf, c1, c2);
  lap_vec_k<<<1024, 256, 0, stream>>>(graph, dd, c1, c12, 1);

  // co-launched: H02 (z=0) || g12T (z=1)
  gg_k<<<dim3(16, 16, 2), 256, 0, stream>>>(
      H0bf, e2wbf, emb2_b, H02, g2tbf, g1tbf, g12T);

  // attention
  hmix_k<<<256, 256, 0, stream>>>(H02, att_W, att_a, hTbf, e1, e2);
  att_rowstats_k<<<Bn * Nn, 256, 0, stream>>>(e1, e2, rsinv);
  pxa_k<<<dim3(16, 16), 512, 0, stream>>>(hTbf, e1, e2, rsinv, XAbf, XAT);

  // learned graph: ge = [XAT|glE] @ W2^T ; den[m] = sum_k exp(relu(ge ge^T))
  mgemm_k<4, 0, 1><<<dim3(16, 2, 16), 256, 0, stream>>>(
      XAT, w2bf, glEbf, gebf, nullptr,
      nullptr, nullptr, nullptr, nullptr,
      128, 64, 128, 128, PB, 0, (long)Nn * 128);
  mgemm_k<6, 0, 0><<<dim3(16, 16, 16), 256, 0, stream>>>(
      gebf, gebf, nullptr, nullptr, nullptr,
      nullptr, nullptr, nullptr, den,
      128, 128, 128, 1024, (long)Nn * 128, (long)Nn * 128, NNc);

  // flash-style u/w + ymix (ST regenerated from L2-resident ge)
  fuw_k<<<dim3(16, 16), 256, 0, stream>>>(
      gebf, den, g12T, XAbf, XAT, Acat, lin2_b, lb2, c2, c12,
      y1b, y2b, part);

  // fused final (LN finish + gelu + cell update)
  final_k<<<BEN / 256, 256, 0, stream>>>(y1b, y2b, XAbf, ct, ln_w, ln_b,
                                         part, out);
}

// Round 19
// 146.891 us; speedup vs baseline: 1.0004x; 1.0004x over previous
//
#include <hip/hip_runtime.h>
#include <hip/hip_bf16.h>
#include <math.h>

constexpr int Bn  = 16;
constexpr int Nn  = 1024;
constexpr int CIN = 3;
constexpr int En  = 64;
constexpr int Gn  = 16;
constexpr int PB  = En * Nn;      // 65536
constexpr int BEN = Bn * PB;      // 1,048,576
constexpr int NNc = Nn * Nn;      // 1,048,576

typedef __attribute__((ext_vector_type(8))) short bf16x8;
typedef __attribute__((ext_vector_type(4))) float f32x4;

__device__ inline ushort f2b(float f) {
  union { __hip_bfloat16 h; ushort u; } v;
  v.h = __float2bfloat16(f);
  return v.u;
}
__device__ inline float b2f(ushort u) {
  union { ushort u; __hip_bfloat16 h; } v;
  v.u = u;
  return __bfloat162float(v.h);
}

// ---------------------------------------------------------------------------
// MFMA bf16 GEMM core: 64x64 tile, 4 waves, BK=64.
// ASPLIT: A = [XAT | glEbf]. EPI: 4 C16 store; 6 den-only (atomics, no store).
// ---------------------------------------------------------------------------
template <int EPI, int BGEN, int ASPLIT>
__global__ __launch_bounds__(256) void mgemm_k(
    const ushort* __restrict__ A, const ushort* __restrict__ Bt,
    const ushort* __restrict__ A2,
    ushort* __restrict__ C16, ushort* __restrict__ C16b,
    const float* __restrict__ q1, const float* __restrict__ q2,
    const float* __restrict__ q4, float* __restrict__ dout,
    int K, int lda, int ldb, int ldc, long sA, long sB, long sC) {
  __shared__ ushort Al[5120];
  __shared__ ushort Bl[5120];
  int tid = threadIdx.x;
  int w = tid >> 6, l = tid & 63;
  int wm = (w >> 1) << 5, wn = (w & 1) << 5;
  int m0 = blockIdx.x << 6, n0 = blockIdx.y << 6, z = blockIdx.z;
  const ushort* Ab = A + (size_t)z * sA;
  const ushort* Bb = Bt + (size_t)z * sB;
  int r0 = tid >> 3, c0 = (tid & 7) << 3;
  int lo0 = (c0 >> 5) * 2560 + r0 * 40 + (c0 & 31);
  int lo1 = (c0 >> 5) * 2560 + (r0 + 32) * 40 + (c0 & 31);
  int fr = l & 15, fg = l >> 4;
  f32x4 acc[2][2] = {};

  int4 ra0, ra1, rb0, rb1;

  auto FETCH = [&](int k0) {
    if (ASPLIT) {
      const ushort* base = (k0 == 0) ? Ab : A2;
      ra0 = *(const int4*)(base + (size_t)(m0 + r0) * 64 + c0);
      ra1 = *(const int4*)(base + (size_t)(m0 + r0 + 32) * 64 + c0);
    } else {
      ra0 = *(const int4*)(Ab + (size_t)(m0 + r0) * lda + k0 + c0);
      ra1 = *(const int4*)(Ab + (size_t)(m0 + r0 + 32) * lda + k0 + c0);
    }
    rb0 = *(const int4*)(Bb + (size_t)(n0 + r0) * ldb + k0 + c0);
    rb1 = *(const int4*)(Bb + (size_t)(n0 + r0 + 32) * ldb + k0 + c0);
  };

  auto STORE = [&]() {
    *(int4*)&Al[lo0] = ra0;
    *(int4*)&Al[lo1] = ra1;
    *(int4*)&Bl[lo0] = rb0;
    *(int4*)&Bl[lo1] = rb1;
  };

  FETCH(0);
  for (int k0 = 0; k0 < K; k0 += 64) {
    __syncthreads();
    STORE();
    __syncthreads();
    if (k0 + 64 < K) FETCH(k0 + 64);
#pragma unroll
    for (int kk = 0; kk < 2; ++kk) {
      bf16x8 af[2], bfv[2];
#pragma unroll
      for (int i = 0; i < 2; ++i)
        af[i] = *(const bf16x8*)&Al[kk * 2560 + (wm + (i << 4) + fr) * 40 + (fg << 3)];
#pragma unroll
      for (int j = 0; j < 2; ++j)
        bfv[j] = *(const bf16x8*)&Bl[kk * 2560 + (wn + (j << 4) + fr) * 40 + (fg << 3)];
#pragma unroll
      for (int i = 0; i < 2; ++i)
#pragma unroll
        for (int j = 0; j < 2; ++j)
          acc[i][j] = __builtin_amdgcn_mfma_f32_16x16x32_bf16(
              af[i], bfv[j], acc[i][j], 0, 0, 0);
    }
  }

  int crb = (l >> 4) << 2, ccol = l & 15;
  if (EPI == 6) {
    // den-only: den[m] += sum_col exp(relu(v)); no C store
    float rp[8];
#pragma unroll
    for (int q = 0; q < 8; ++q) rp[q] = 0.f;
#pragma unroll
    for (int i = 0; i < 2; ++i)
#pragma unroll
      for (int j = 0; j < 2; ++j)
#pragma unroll
        for (int r = 0; r < 4; ++r) {
          float v = fmaxf(acc[i][j][r], 0.f);
          rp[i * 4 + r] += __expf(v);
        }
    __syncthreads();
    float* rs = (float*)Al;
    if (tid < 64) rs[tid] = 0.f;
    __syncthreads();
#pragma unroll
    for (int i = 0; i < 2; ++i)
#pragma unroll
      for (int r = 0; r < 4; ++r) {
        float p = rp[i * 4 + r];
#pragma unroll
        for (int msk = 1; msk < 16; msk <<= 1) p += __shfl_xor(p, msk);
        if ((l & 15) == 0) atomicAdd(&rs[wm + (i << 4) + crb + r], p);
      }
    __syncthreads();
    if (tid < 64) atomicAdd(&dout[((size_t)z << 10) + m0 + tid], rs[tid]);
  } else {
#pragma unroll
    for (int i = 0; i < 2; ++i)
#pragma unroll
      for (int j = 0; j < 2; ++j)
#pragma unroll
        for (int r = 0; r < 4; ++r) {
          int row = m0 + wm + (i << 4) + crb + r;
          int col = n0 + wn + (j << 4) + ccol;
          size_t off = (size_t)z * sC + (size_t)row * ldc + col;
          if (EPI == 4) C16[off] = f2b(acc[i][j][r]);
        }
  }
}

// ---------------------------------------------------------------------------
// pxa_k: split-K wave-groups + depth-2 pipeline.
// P generated in staging; out: XAbf [b][e][n] = relu(P@h), XAT [b][n][e].
// ---------------------------------------------------------------------------
__global__ __launch_bounds__(512) void pxa_k(
    const ushort* __restrict__ hT, const float* __restrict__ e1,
    const float* __restrict__ e2, const float* __restrict__ rsinv,
    ushort* __restrict__ XAbf, ushort* __restrict__ XAT) {
  __shared__ ushort Al[2][5120];
  __shared__ ushort Bl[2][5120];
  __shared__ float cmb[256 * 16];
  int tid = threadIdx.x;
  int grp = tid >> 8;
  int t = tid & 255;
  int w = t >> 6, l = t & 63;
  int wm = (w >> 1) << 5, wn = (w & 1) << 5;
  int n0 = blockIdx.x << 6, z = blockIdx.y;
  int kbase = grp << 9;
  const ushort* Ab = hT + (size_t)z * PB;
  int r0 = t >> 3, c0 = (t & 7) << 3;
  int lo0 = (c0 >> 5) * 2560 + r0 * 40 + (c0 & 31);
  int lo1 = (c0 >> 5) * 2560 + (r0 + 32) * 40 + (c0 & 31);
  int fr = l & 15, fg = l >> 4;
  f32x4 acc[2][2] = {};

  const float* e1b = e1 + (z << 10);
  const float* rsb = rsinv + (z << 10);
  float ei0 = e1b[n0 + r0], sc0 = rsb[n0 + r0];
  float ei1 = e1b[n0 + r0 + 32], sc1 = rsb[n0 + r0 + 32];

  int4 raA0, raA1, raB0, raB1;
  float fA[8], fB[8];

  auto FETCHA = [&](int k0) {
    raA0 = *(const int4*)(Ab + (size_t)r0 * 1024 + k0 + c0);
    raA1 = *(const int4*)(Ab + (size_t)(r0 + 32) * 1024 + k0 + c0);
    const float* e2b = e2 + (z << 10) + k0 + c0;
    *(float4*)&fA[0] = *(const float4*)(e2b);
    *(float4*)&fA[4] = *(const float4*)(e2b + 4);
  };
  auto FETCHB = [&](int k0) {
    raB0 = *(const int4*)(Ab + (size_t)r0 * 1024 + k0 + c0);
    raB1 = *(const int4*)(Ab + (size_t)(r0 + 32) * 1024 + k0 + c0);
    const float* e2b = e2 + (z << 10) + k0 + c0;
    *(float4*)&fB[0] = *(const float4*)(e2b);
    *(float4*)&fB[4] = *(const float4*)(e2b + 4);
  };
  auto STOREA = [&]() {
    *(int4*)&Al[grp][lo0] = raA0;
    *(int4*)&Al[grp][lo1] = raA1;
    ushort o0[8], o1[8];
#pragma unroll
    for (int q = 0; q < 8; ++q) {
      float z0 = ei0 + fA[q];
      z0 = z0 >= 0.f ? z0 : 0.01f * z0;
      o0[q] = f2b(__expf(z0) * sc0);
      float z1 = ei1 + fA[q];
      z1 = z1 >= 0.f ? z1 : 0.01f * z1;
      o1[q] = f2b(__expf(z1) * sc1);
    }
    *(int4*)&Bl[grp][lo0] = *(int4*)o0;
    *(int4*)&Bl[grp][lo1] = *(int4*)o1;
  };
  auto STOREB = [&]() {
    *(int4*)&Al[grp][lo0] = raB0;
    *(int4*)&Al[grp][lo1] = raB1;
    ushort o0[8], o1[8];
#pragma unroll
    for (int q = 0; q < 8; ++q) {
      float z0 = ei0 + fB[q];
      z0 = z0 >= 0.f ? z0 : 0.01f * z0;
      o0[q] = f2b(__expf(z0) * sc0);
      float z1 = ei1 + fB[q];
      z1 = z1 >= 0.f ? z1 : 0.01f * z1;
      o1[q] = f2b(__expf(z1) * sc1);
    }
    *(int4*)&Bl[grp][lo0] = *(int4*)o0;
    *(int4*)&Bl[grp][lo1] = *(int4*)o1;
  };
  auto MFMAS = [&]() {
#pragma unroll
    for (int kk = 0; kk < 2; ++kk) {
      bf16x8 af[2], bfv[2];
#pragma unroll
      for (int i = 0; i < 2; ++i)
        af[i] = *(const bf16x8*)&Al[grp][kk * 2560 + (wm + (i << 4) + fr) * 40 + (fg << 3)];
#pragma unroll
      for (int j = 0; j < 2; ++j)
        bfv[j] = *(const bf16x8*)&Bl[grp][kk * 2560 + (wn + (j << 4) + fr) * 40 + (fg << 3)];
#pragma unroll
      for (int i = 0; i < 2; ++i)
#pragma unroll
        for (int j = 0; j < 2; ++j)
          acc[i][j] = __builtin_amdgcn_mfma_f32_16x16x32_bf16(
              af[i], bfv[j], acc[i][j], 0, 0, 0);
    }
  };

  FETCHA(kbase);
  FETCHB(kbase + 64);
  for (int ks = 0; ks < 8; ks += 2) {
    __syncthreads();
    STOREA();
    __syncthreads();
    if (ks + 2 < 8) FETCHA(kbase + ((ks + 2) << 6));
    MFMAS();
    __syncthreads();
    STOREB();
    __syncthreads();
    if (ks + 3 < 8) FETCHB(kbase + ((ks + 3) << 6));
    MFMAS();
  }

  __syncthreads();
  if (grp == 1) {
    float* d = cmb + t * 16;
#pragma unroll
    for (int i = 0; i < 2; ++i)
#pragma unroll
      for (int j = 0; j < 2; ++j)
#pragma unroll
        for (int r = 0; r < 4; ++r) d[((i << 1) + j) * 4 + r] = acc[i][j][r];
  }
  __syncthreads();
  if (grp == 1) return;
  const float* s = cmb + t * 16;
#pragma unroll
  for (int i = 0; i < 2; ++i)
#pragma unroll
    for (int j = 0; j < 2; ++j)
#pragma unroll
      for (int r = 0; r < 4; ++r) acc[i][j][r] += s[((i << 1) + j) * 4 + r];

  int crb = (l >> 4) << 2, ccol = l & 15;
#pragma unroll
  for (int i = 0; i < 2; ++i)
#pragma unroll
    for (int j = 0; j < 2; ++j)
#pragma unroll
      for (int r = 0; r < 4; ++r) {
        int row = wm + (i << 4) + crb + r;        // e index
        int col = n0 + wn + (j << 4) + ccol;      // node index
        float v = fmaxf(acc[i][j][r], 0.f);
        XAbf[(size_t)z * PB + (size_t)row * 1024 + col] = f2b(v);
        XAT[(size_t)z * PB + (size_t)col * 64 + row] = f2b(v);
      }
}

// ---------------------------------------------------------------------------
// gg_k (depth-2), grid (16,16,2).
// z=0: H02 = H0 @ emb2_w^T + emb2_b (fp32); z=1: g12T = g2t @ g1t (bf16).
// ---------------------------------------------------------------------------
__global__ __launch_bounds__(256) void gg_k(
    const ushort* __restrict__ H0bf, const ushort* __restrict__ e2wbf,
    const float* __restrict__ emb2b, float* __restrict__ H02,
    const ushort* __restrict__ g2t, const ushort* __restrict__ g1t,
    ushort* __restrict__ g12T) {
  __shared__ ushort Al[5120];
  __shared__ ushort Bl[5120];
  int tid = threadIdx.x;
  int w = tid >> 6, l = tid & 63;
  int wm = (w >> 1) << 5, wn = (w & 1) << 5;
  int m0 = blockIdx.x << 6, n0 = blockIdx.y << 6;
  int job = blockIdx.z;
  const ushort* Ab = job ? g2t : H0bf;
  int r0 = tid >> 3, c0 = (tid & 7) << 3;
  int lo0 = (c0 >> 5) * 2560 + r0 * 40 + (c0 & 31);
  int lo1 = (c0 >> 5) * 2560 + (r0 + 32) * 40 + (c0 & 31);
  int fr = l & 15, fg = l >> 4;
  f32x4 acc[2][2] = {};
  int4 raA0, raA1, rbA0, rbA1;
  int4 raB0, raB1, rbB0, rbB1;

  auto FETCHA = [&](int k0) {
    raA0 = *(const int4*)(Ab + (size_t)(m0 + r0) * 1024 + k0 + c0);
    raA1 = *(const int4*)(Ab + (size_t)(m0 + r0 + 32) * 1024 + k0 + c0);
    if (job) {
      rbA0 = *(const int4*)(g1t + (size_t)(k0 + r0) * 1024 + n0 + c0);
      rbA1 = *(const int4*)(g1t + (size_t)(k0 + r0 + 32) * 1024 + n0 + c0);
    } else {
      rbA0 = *(const int4*)(e2wbf + (size_t)(n0 + r0) * 1024 + k0 + c0);
      rbA1 = *(const int4*)(e2wbf + (size_t)(n0 + r0 + 32) * 1024 + k0 + c0);
    }
  };
  auto FETCHB = [&](int k0) {
    raB0 = *(const int4*)(Ab + (size_t)(m0 + r0) * 1024 + k0 + c0);
    raB1 = *(const int4*)(Ab + (size_t)(m0 + r0 + 32) * 1024 + k0 + c0);
    if (job) {
      rbB0 = *(const int4*)(g1t + (size_t)(k0 + r0) * 1024 + n0 + c0);
      rbB1 = *(const int4*)(g1t + (size_t)(k0 + r0 + 32) * 1024 + n0 + c0);
    } else {
      rbB0 = *(const int4*)(e2wbf + (size_t)(n0 + r0) * 1024 + k0 + c0);
      rbB1 = *(const int4*)(e2wbf + (size_t)(n0 + r0 + 32) * 1024 + k0 + c0);
    }
  };
  auto STOREA = [&]() {
    *(int4*)&Al[lo0] = raA0;
    *(int4*)&Al[lo1] = raA1;
    if (job) {
      const ushort* p0 = (const ushort*)&rbA0;
      const ushort* p1 = (const ushort*)&rbA1;
#pragma unroll
      for (int q = 0; q < 8; ++q) {
        Bl[(c0 + q) * 40 + r0] = p0[q];
        Bl[2560 + (c0 + q) * 40 + r0] = p1[q];
      }
    } else {
      *(int4*)&Bl[lo0] = rbA0;
      *(int4*)&Bl[lo1] = rbA1;
    }
  };
  auto STOREB = [&]() {
    *(int4*)&Al[lo0] = raB0;
    *(int4*)&Al[lo1] = raB1;
    if (job) {
      const ushort* p0 = (const ushort*)&rbB0;
      const ushort* p1 = (const ushort*)&rbB1;
#pragma unroll
      for (int q = 0; q < 8; ++q) {
        Bl[(c0 + q) * 40 + r0] = p0[q];
        Bl[2560 + (c0 + q) * 40 + r0] = p1[q];
      }
    } else {
      *(int4*)&Bl[lo0] = rbB0;
      *(int4*)&Bl[lo1] = rbB1;
    }
  };
  auto MFMAS = [&]() {
#pragma unroll
    for (int kk = 0; kk < 2; ++kk) {
      bf16x8 af[2], bfv[2];
#pragma unroll
      for (int i = 0; i < 2; ++i)
        af[i] = *(const bf16x8*)&Al[kk * 2560 + (wm + (i << 4) + fr) * 40 + (fg << 3)];
#pragma unroll
      for (int j = 0; j < 2; ++j)
        bfv[j] = *(const bf16x8*)&Bl[kk * 2560 + (wn + (j << 4) + fr) * 40 + (fg << 3)];
#pragma unroll
      for (int i = 0; i < 2; ++i)
#pragma unroll
        for (int j = 0; j < 2; ++j)
          acc[i][j] = __builtin_amdgcn_mfma_f32_16x16x32_bf16(
              af[i], bfv[j], acc[i][j], 0, 0, 0);
    }
  };

  FETCHA(0);
  FETCHB(64);
  for (int ks = 0; ks < 16; ks += 2) {
    __syncthreads();
    STOREA();
    __syncthreads();
    if (ks + 2 < 16) FETCHA((ks + 2) << 6);
    MFMAS();
    __syncthreads();
    STOREB();
    __syncthreads();
    if (ks + 3 < 16) FETCHB((ks + 3) << 6);
    MFMAS();
  }

  int crb = (l >> 4) << 2, ccol = l & 15;
#pragma unroll
  for (int i = 0; i < 2; ++i)
#pragma unroll
    for (int j = 0; j < 2; ++j)
#pragma unroll
      for (int r = 0; r < 4; ++r) {
        int row = m0 + wm + (i << 4) + crb + r;
        int col = n0 + wn + (j << 4) + ccol;
        float v = acc[i][j][r];
        if (job) g12T[(size_t)row * 1024 + col] = f2b(v);
        else H02[(size_t)row * 1024 + col] = v + emb2b[col];
      }
}

// ---------------------------------------------------------------------------
// fuw_k (R19): flash-style u/w + ymix, with XCD-aware block swizzle so each
// XCD owns 2 batches (per-XCD L2 working set ~2.8MB < 4MB).
// Per K-step: stage geK/XA/g12 (L2) -> QK MFMA -> exp*rcp(den) -> pack to
// A-layout LDS -> u/w MFMA. Then colS, UW, phase C (y1/y2 + rank1 + LN).
// grid 256 linear blocks, 256 threads.
// ---------------------------------------------------------------------------
__global__ __launch_bounds__(256) void fuw_k(
    const ushort* __restrict__ ge, const float* __restrict__ den,
    const ushort* __restrict__ g12T, const ushort* __restrict__ XAbf,
    const ushort* __restrict__ XAT, const ushort* __restrict__ Acat,
    const float* __restrict__ b2, const float* __restrict__ lb2,
    const float* __restrict__ c2, const float* __restrict__ c12,
    ushort* __restrict__ y1, ushort* __restrict__ y2,
    float* __restrict__ part) {
  __shared__ ushort geM[4 * 2560];   // [4 c-chunks][64][40] (m-tile ge rows)
  __shared__ ushort geK[4 * 2560];   // per-step k-tile ge rows
  __shared__ ushort Au[2 * 2560];    // regenerated ST tile (A layout)
  __shared__ ushort Ag[2 * 2560];    // g12 tile
  __shared__ ushort Bx[2 * 2560];    // XA tile
  __shared__ ushort UW[64 * 132];
  __shared__ float rden[1024];
  __shared__ float colS[64];
  int tid = threadIdx.x;
  int w = tid >> 6, l = tid & 63;
  int wm = (w >> 1) << 5, wn = (w & 1) << 5;
  // XCD-aware swizzle: linear id L -> XCD L%8 (round-robin dispatch, m09).
  // Assign XCD k the batches {2k, 2k+1} so per-XCD L2 holds its ge/XA set.
  int lid = blockIdx.x + (blockIdx.y << 4);   // 0..255
  int xcd = lid & 7;
  int slot = lid >> 3;                        // 0..31
  int z = (xcd << 1) + (slot >> 4);           // batch 0..15
  int m0 = (slot & 15) << 6;                  // m-tile
  const ushort* geb = ge + (size_t)z * Nn * 128;
  const ushort* Bb = XAbf + (size_t)z * PB;
  int r0 = tid >> 3, c0 = (tid & 7) << 3;
  int lo0 = (c0 >> 5) * 2560 + r0 * 40 + (c0 & 31);
  int lo1 = (c0 >> 5) * 2560 + (r0 + 32) * 40 + (c0 & 31);
  int fr = l & 15, fg = l >> 4;
  int crb = (l >> 4) << 2, ccol = l & 15;

  // preload rcp(den) + zero colS
  {
    float4 d4 = *(const float4*)(den + (z << 10) + (tid << 2));
    rden[(tid << 2) + 0] = __builtin_amdgcn_rcpf(d4.x);
    rden[(tid << 2) + 1] = __builtin_amdgcn_rcpf(d4.y);
    rden[(tid << 2) + 2] = __builtin_amdgcn_rcpf(d4.z);
    rden[(tid << 2) + 3] = __builtin_amdgcn_rcpf(d4.w);
  }
  if (tid < 64) colS[tid] = 0.f;

  // stage geM once: rows m0+r0 / m0+r0+32, c-halves h = 0,1
#pragma unroll
  for (int h = 0; h < 2; ++h) {
    int ch = (h << 1) + (c0 >> 5);
    *(int4*)&geM[ch * 2560 + r0 * 40 + (c0 & 31)] =
        *(const int4*)(geb + (size_t)(m0 + r0) * 128 + h * 64 + c0);
    *(int4*)&geM[ch * 2560 + (r0 + 32) * 40 + (c0 & 31)] =
        *(const int4*)(geb + (size_t)(m0 + r0 + 32) * 128 + h * 64 + c0);
  }

  f32x4 au[2][2] = {};
  f32x4 aw[2][2] = {};
  float csr[8];
#pragma unroll
  for (int q = 0; q < 8; ++q) csr[q] = 0.f;

  int4 gk0, gk1, gk2, gk3, bx0, bx1, ag0, ag1;
  auto FETCH = [&](int k0) {
    gk0 = *(const int4*)(geb + (size_t)(k0 + r0) * 128 + c0);
    gk1 = *(const int4*)(geb + (size_t)(k0 + r0 + 32) * 128 + c0);
    gk2 = *(const int4*)(geb + (size_t)(k0 + r0) * 128 + 64 + c0);
    gk3 = *(const int4*)(geb + (size_t)(k0 + r0 + 32) * 128 + 64 + c0);
    bx0 = *(const int4*)(Bb + (size_t)r0 * 1024 + k0 + c0);
    bx1 = *(const int4*)(Bb + (size_t)(r0 + 32) * 1024 + k0 + c0);
    ag0 = *(const int4*)(g12T + (size_t)(m0 + r0) * 1024 + k0 + c0);
    ag1 = *(const int4*)(g12T + (size_t)(m0 + r0 + 32) * 1024 + k0 + c0);
  };
  auto STORE = [&]() {
    int ch = c0 >> 5;
    *(int4*)&geK[ch * 2560 + r0 * 40 + (c0 & 31)] = gk0;
    *(int4*)&geK[ch * 2560 + (r0 + 32) * 40 + (c0 & 31)] = gk1;
    *(int4*)&geK[(2 + ch) * 2560 + r0 * 40 + (c0 & 31)] = gk2;
    *(int4*)&geK[(2 + ch) * 2560 + (r0 + 32) * 40 + (c0 & 31)] = gk3;
    *(int4*)&Bx[lo0] = bx0;
    *(int4*)&Bx[lo1] = bx1;
    *(int4*)&Ag[lo0] = ag0;
    *(int4*)&Ag[lo1] = ag1;
  };

  FETCH(0);
  for (int k0 = 0; k0 < 1024; k0 += 64) {
    __syncthreads();
    STORE();
    __syncthreads();
    if (k0 + 64 < 1024) FETCH(k0 + 64);
    // QK: sym tile [m][k] = geM @ geK^T over c=128 (4 chunks of 32)
    f32x4 as[2][2] = {};
#pragma unroll
    for (int kk = 0; kk < 4; ++kk) {
      bf16x8 am[2], bk[2];
#pragma unroll
      for (int i = 0; i < 2; ++i)
        am[i] = *(const bf16x8*)&geM[kk * 2560 + (wm + (i << 4) + fr) * 40 + (fg << 3)];
#pragma unroll
      for (int j = 0; j < 2; ++j)
        bk[j] = *(const bf16x8*)&geK[kk * 2560 + (wn + (j << 4) + fr) * 40 + (fg << 3)];
#pragma unroll
      for (int i = 0; i < 2; ++i)
#pragma unroll
        for (int j = 0; j < 2; ++j)
          as[i][j] = __builtin_amdgcn_mfma_f32_16x16x32_bf16(
              am[i], bk[j], as[i][j], 0, 0, 0);
    }
    // exp * rcp(den) -> pack into Au (A layout); colS partials
#pragma unroll
    for (int i = 0; i < 2; ++i)
#pragma unroll
      for (int j = 0; j < 2; ++j)
#pragma unroll
        for (int r = 0; r < 4; ++r) {
          int row = wm + (i << 4) + crb + r;
          int col = wn + (j << 4) + ccol;
          float v = fmaxf(as[i][j][r], 0.f);
          float st = __expf(v) * rden[k0 + col];
          csr[i * 4 + r] += st;
          Au[(col >> 5) * 2560 + row * 40 + (col & 31)] = f2b(st);
        }
    __syncthreads();
    // u/w MFMA over this 64-k step
#pragma unroll
    for (int kk = 0; kk < 2; ++kk) {
      bf16x8 fu[2], fw[2], fb[2];
#pragma unroll
      for (int i = 0; i < 2; ++i) {
        int off = kk * 2560 + (wm + (i << 4) + fr) * 40 + (fg << 3);
        fu[i] = *(const bf16x8*)&Au[off];
        fw[i] = *(const bf16x8*)&Ag[off];
      }
#pragma unroll
      for (int j = 0; j < 2; ++j)
        fb[j] = *(const bf16x8*)&Bx[kk * 2560 + (wn + (j << 4) + fr) * 40 + (fg << 3)];
#pragma unroll
      for (int i = 0; i < 2; ++i)
#pragma unroll
        for (int j = 0; j < 2; ++j) {
          au[i][j] = __builtin_amdgcn_mfma_f32_16x16x32_bf16(
              fu[i], fb[j], au[i][j], 0, 0, 0);
          aw[i][j] = __builtin_amdgcn_mfma_f32_16x16x32_bf16(
              fw[i], fb[j], aw[i][j], 0, 0, 0);
        }
    }
  }

  // colS: reduce across the 16 col-lanes, then LDS atomics
#pragma unroll
  for (int q = 0; q < 8; ++q) {
#pragma unroll
    for (int msk = 1; msk < 16; msk <<= 1) csr[q] += __shfl_xor(csr[q], msk);
  }
  if ((l & 15) == 0) {
#pragma unroll
    for (int i = 0; i < 2; ++i)
#pragma unroll
      for (int r = 0; r < 4; ++r)
        atomicAdd(&colS[wm + (i << 4) + crb + r], csr[i * 4 + r]);
  }
  __syncthreads();

  // UW fill: u (+ xa^T aux) and w (B-operand layout for phase C)
#pragma unroll
  for (int i = 0; i < 2; ++i)
#pragma unroll
    for (int j = 0; j < 2; ++j)
#pragma unroll
      for (int r = 0; r < 4; ++r) {
        int node = wm + (i << 4) + crb + r;
        int e = wn + (j << 4) + ccol;
        float uv = au[i][j][r] +
                   b2f(XAT[(size_t)z * PB + (size_t)(m0 + node) * 64 + e]);
        UW[node * 132 + e] = f2b(uv);
        UW[node * 132 + 64 + e] = f2b(aw[i][j][r]);
      }
  __syncthreads();

  // phase C: y = Acat @ [u;w] (K=128). waves 0,1 -> y1; 2,3 -> y2.
  int half = w >> 1;
  int mrow = (w & 1) << 5;
  const ushort* Ac = Acat + half * 8192;
  bf16x8 af[2][4];
#pragma unroll
  for (int i = 0; i < 2; ++i)
#pragma unroll
    for (int s = 0; s < 4; ++s)
      af[i][s] = *(const bf16x8*)&Ac[(mrow + i * 16 + fr) * 128 + s * 32 + fg * 8];
  f32x4 acc[2][4] = {};
#pragma unroll
  for (int s = 0; s < 4; ++s) {
    bf16x8 bv[4];
#pragma unroll
    for (int j = 0; j < 4; ++j)
      bv[j] = *(const bf16x8*)&UW[(j * 16 + fr) * 132 + s * 32 + fg * 8];
#pragma unroll
    for (int i = 0; i < 2; ++i)
#pragma unroll
      for (int j = 0; j < 4; ++j)
        acc[i][j] = __builtin_amdgcn_mfma_f32_16x16x32_bf16(
            af[i][s], bv[j], acc[i][j], 0, 0, 0);
  }
  ushort* Y = half ? y2 : y1;
  float ysum = 0.f, yss = 0.f;
#pragma unroll
  for (int i = 0; i < 2; ++i)
#pragma unroll
    for (int j = 0; j < 4; ++j) {
      int node = (j << 4) + ccol;
      float rk = 0.f, r12 = 0.f;
      if (half) {
        rk = 1.0f + colS[node] + c2[m0 + node];
        r12 = c12[m0 + node];
      }
#pragma unroll
      for (int r = 0; r < 4; ++r) {
        int row = mrow + (i << 4) + crb + r;
        float v = acc[i][j][r];
        if (half) v += b2[row] * rk + lb2[row] * r12;
        Y[(size_t)z * PB + (size_t)row * 1024 + m0 + node] = f2b(v);
        ysum += v;
        yss = fmaf(v, v, yss);
      }
    }
#pragma unroll
  for (int msk = 1; msk < 64; msk <<= 1) {
    ysum += __shfl_xor(ysum, msk);
    yss += __shfl_xor(yss, msk);
  }
  if (l == 0) {
    atomicAdd(&part[half * 32 + z * 2], ysum);
    atomicAdd(&part[half * 32 + z * 2 + 1], yss);
  }
}

// ---------------------------------------------------------------------------
// prep0_k: [0,2048) lap rowsum; [2048,2402) Acat/lb2/part0/glE/den0;
// [2402,10658) weight casts + embedding.
// ---------------------------------------------------------------------------
__global__ __launch_bounds__(256) void prep0_k(
    const float* __restrict__ graph, float* __restrict__ dd,
    const float* __restrict__ L1, const float* __restrict__ L2,
    const float* __restrict__ b2, float* __restrict__ lb2,
    ushort* __restrict__ Acat, const float* __restrict__ GL,
    const float* __restrict__ GLlin_w, ushort* __restrict__ glEbf,
    const float* __restrict__ emb2w, const float* __restrict__ w2,
    ushort* __restrict__ e2wbf, ushort* __restrict__ w2bf,
    const float* __restrict__ x, const float* __restrict__ emb_w,
    const float* __restrict__ emb_b, ushort* __restrict__ H0,
    float* __restrict__ part, float* __restrict__ den) {
  int blk = blockIdx.x, tid = threadIdx.x;
  if (blk < 2048) {
    const float* row = graph + (size_t)blk * Nn;
    float s = 0.0f;
    for (int j = tid; j < Nn; j += 256) s += row[j];
    __shared__ float red[256];
    red[tid] = s;
    __syncthreads();
    for (int st = 128; st > 0; st >>= 1) {
      if (tid < st) red[tid] += red[tid + st];
      __syncthreads();
    }
    if (tid == 0) {
      float t = red[0] + 1.0f;
      dd[blk] = (t > 0.0f) ? rsqrtf(t) : 0.0f;
    }
  } else if (blk < 2402) {
    int pblk = blk - 2048;
    if (pblk < 32) {
      int mat = pblk >> 4;
      int o = ((pblk & 15) << 8) + tid;
      int e = o >> 6, c = o & 63;
      const float* L = mat ? L2 : L1;
      float s = 0.f;
#pragma unroll
      for (int t = 0; t < 64; ++t) s = fmaf(L[e * 64 + t], L[t * 64 + c], s);
      Acat[mat * 8192 + e * 128 + 64 + c] = f2b(s);
    } else if (pblk == 32) {
      for (int t = tid; t < 8192; t += 256) {
        int w = t >> 12, rem = t & 4095, m = rem >> 6, k = rem & 63;
        Acat[w * 8192 + m * 128 + k] = f2b((w ? L2 : L1)[m * 64 + k]);
      }
    } else if (pblk == 33) {
      if (tid < 64) {
        float s = 0.f;
#pragma unroll
        for (int c = 0; c < 64; ++c) s = fmaf(L2[tid * 64 + c], b2[c], s);
        lb2[tid] = s;
      } else if (tid < 128) {
        part[tid - 64] = 0.f;
      }
    } else if (pblk < 290) {
      int idx = (pblk - 34) * 256 + tid;  // < 65536
      int n = idx >> 6, e = idx & 63;
      float s = 0.0f;
#pragma unroll
      for (int g = 0; g < Gn; ++g)
        s = fmaf(GL[n * Gn + g], GLlin_w[e * Gn + g], s);
      glEbf[idx] = f2b(s);
    } else {
      int idx = (pblk - 290) * 256 + tid;  // < 16384
      den[idx] = 0.f;
    }
  } else {
    int cblk = blk - 2402;
    if (cblk < 4160) {
      int idx = cblk * 256 + tid;
      if (idx < NNc) e2wbf[idx] = f2b(emb2w[idx]);
      else if (idx < NNc + 16384) w2bf[idx - NNc] = f2b(w2[idx - NNc]);
    } else {
      int idx = (cblk - 4160) * 256 + tid;  // < BEN
      int b = idx >> 16, r = idx & 65535, e = r >> 10, n = r & 1023;
      const float* xb = x + (size_t)b * (CIN * Nn);
      float s = emb_b[e] + emb_w[e * 3 + 0] * xb[n] +
                emb_w[e * 3 + 1] * xb[Nn + n] +
                emb_w[e * 3 + 2] * xb[2 * Nn + n];
      s = s >= 0.0f ? s : 0.01f * s;
      H0[idx] = f2b(s);
    }
  }
}

// One pass over graph row (g,m): write g_t row m (bf16) + c_g[m].
__global__ __launch_bounds__(256) void lap_fused_k(
    const float* __restrict__ graph, const float* __restrict__ dd,
    ushort* __restrict__ g1t, ushort* __restrict__ g2t,
    float* __restrict__ c1, float* __restrict__ c2) {
  int gi = blockIdx.x;
  int g = gi >> 10, m = gi & 1023;
  const float* grow = graph + (size_t)gi * Nn;
  const float* ddg = dd + (g << 10);
  float ddm = ddg[m];
  ushort* gt = (g ? g2t : g1t) + (size_t)m * Nn;
  int tid = threadIdx.x;
  float s = 0.0f;
  for (int n = tid; n < Nn; n += 256) {
    float t = ddg[n] * grow[n];
    s += t;
    float v = t * ddm + (n == m ? ddm * ddm : 0.f);
    gt[n] = f2b(v);
  }
  __shared__ float red[256];
  red[tid] = s;
  __syncthreads();
  for (int st = 128; st > 0; st >>= 1) {
    if (tid < st) red[tid] += red[tid + st];
    __syncthreads();
  }
  if (tid == 0) (g ? c2 : c1)[m] = ddm * (red[0] + ddm);
}

// out[m] = lap-column action with vector vin (for c12)
__global__ __launch_bounds__(256) void lap_vec_k(
    const float* __restrict__ graph, const float* __restrict__ dd,
    const float* __restrict__ vin, float* __restrict__ out, int g) {
  int m = blockIdx.x;
  int tid = threadIdx.x;
  const float* grow = graph + (size_t)g * NNc + (size_t)m * Nn;
  const float* ddg = dd + (g << 10);
  float s = 0.0f;
  for (int n = tid; n < Nn; n += 256) s += ddg[n] * grow[n] * vin[n];
  __shared__ float red[256];
  red[tid] = s;
  __syncthreads();
  for (int st = 128; st > 0; st >>= 1) {
    if (tid < st) red[tid] += red[tid + st];
    __syncthreads();
  }
  if (tid == 0) out[m] = ddg[m] * (red[0] + ddg[m] * vin[m]);
}

// hT = attW-mix of H02; e1/e2 dots with att_a
__global__ __launch_bounds__(256) void hmix_k(
    const float* __restrict__ H02, const float* __restrict__ attW,
    const float* __restrict__ atta, ushort* __restrict__ hT,
    float* __restrict__ e1, float* __restrict__ e2) {
  __shared__ float Hs[64][65];
  __shared__ float pr1[4][64];
  __shared__ float pr2[4][64];
  int tid = threadIdx.x;
  int blk = blockIdx.x;
  int b = blk >> 4, n0 = (blk & 15) << 6;
  for (int t = tid; t < 4096; t += 256) {
    int e = t >> 6, n = t & 63;
    Hs[e][n] = H02[(size_t)(b * 64 + e) * 1024 + n0 + n];
  }
  __syncthreads();
  int n = tid & 63, epg = tid >> 6;
  float h[16];
#pragma unroll
  for (int i = 0; i < 16; ++i) h[i] = 0.f;
  for (int e = 0; e < 64; ++e) {
    float xv = Hs[e][n];
#pragma unroll
    for (int i = 0; i < 16; ++i)
      h[i] = fmaf(xv, attW[e * 64 + epg * 16 + i], h[i]);
  }
  float s1 = 0.f, s2 = 0.f;
#pragma unroll
  for (int i = 0; i < 16; ++i) {
    int ep = epg * 16 + i;
    hT[(size_t)(b * 64 + ep) * 1024 + n0 + n] = f2b(h[i]);
    s1 = fmaf(h[i], atta[ep], s1);
    s2 = fmaf(h[i], atta[64 + ep], s2);
  }
  pr1[epg][n] = s1;
  pr2[epg][n] = s2;
  __syncthreads();
  if (epg == 0) {
    e1[(b << 10) + n0 + n] = pr1[0][n] + pr1[1][n] + pr1[2][n] + pr1[3][n];
    e2[(b << 10) + n0 + n] = pr2[0][n] + pr2[1][n] + pr2[2][n] + pr2[3][n];
  }
}

// rsinv[i] = 1 / sum_j exp(lrelu(e1_i + e2_j))   (no-max softmax)
__global__ __launch_bounds__(256) void att_rowstats_k(
    const float* __restrict__ e1, const float* __restrict__ e2,
    float* __restrict__ rsinv) {
  int row = blockIdx.x;
  int b = row >> 10;
  const float* e2b = e2 + (b << 10);
  float a = e1[row];
  int tid = threadIdx.x;
  float sm = 0.0f;
#pragma unroll
  for (int l = 0; l < 4; ++l) {
    float v = a + e2b[tid + (l << 8)];
    v = v >= 0.0f ? v : 0.01f * v;
    sm += __expf(v);
  }
  __shared__ float red[256];
  red[tid] = sm;
  __syncthreads();
  for (int s = 128; s > 0; s >>= 1) {
    if (tid < s) red[tid] += red[tid + s];
    __syncthreads();
  }
  if (tid == 0) rsinv[row] = 1.0f / red[0];
}

// final: LN finish + affine + gelu + cell update (y1/y2 bf16)
__global__ __launch_bounds__(256) void final_k(
    const ushort* __restrict__ y1, const ushort* __restrict__ y2,
    const ushort* __restrict__ xabf, const float* __restrict__ ct,
    const float* __restrict__ ln_w, const float* __restrict__ ln_b,
    const float* __restrict__ part, float* __restrict__ out) {
  __shared__ float st[4];
  int idx = blockIdx.x * 256 + threadIdx.x;
  int b = idx >> 16, r = idx & 65535;
  if (threadIdx.x < 2) {
    int wq = threadIdx.x;
    float s = part[wq * 32 + b * 2];
    float ss = part[wq * 32 + b * 2 + 1];
    float mean = s * (1.0f / PB);
    float var = fmaxf(ss * (1.0f / PB) - mean * mean, 0.0f);
    st[wq * 2] = mean;
    st[wq * 2 + 1] = rsqrtf(var + 1e-5f);
  }
  __syncthreads();
  float m1 = st[0], s1 = st[1], m2 = st[2], s2 = st[3];
  float w = ln_w[r], bb = ln_b[r];
  float xn = (b2f(y1[idx]) - m1) * s1 * w + bb;
  float yg = (b2f(y2[idx]) - m2) * s2 * w + bb;
  float g = 0.5f * yg * (1.0f + erff(yg * 0.70710678118654752f));
  float c = ct[idx];
  float cn = xn + g * (c - xn);
  float el = cn > 0.0f ? cn : expm1f(cn);
  float xv = b2f(xabf[idx]);
  out[idx] = xv + g * (el - xv);
  out[BEN + idx] = cn;
}

extern "C" void kernel_launch(void* const* d_in, const int* in_sizes, int n_in,
                              void* d_out, int out_size, void* d_ws,
                              size_t ws_size, hipStream_t stream) {
  const float* x       = (const float*)d_in[0];
  const float* ct      = (const float*)d_in[1];
  const float* graph   = (const float*)d_in[2];
  const float* emb_w   = (const float*)d_in[3];
  const float* emb_b   = (const float*)d_in[4];
  const float* emb2_w  = (const float*)d_in[5];
  const float* emb2_b  = (const float*)d_in[6];
  const float* att_W   = (const float*)d_in[7];
  const float* att_a   = (const float*)d_in[8];
  const float* lin1_w  = (const float*)d_in[10];
  const float* lin2_w  = (const float*)d_in[11];
  const float* lin2_b  = (const float*)d_in[12];
  const float* ln_w    = (const float*)d_in[13];
  const float* ln_b    = (const float*)d_in[14];
  const float* GL      = (const float*)d_in[15];
  const float* GLlin_w = (const float*)d_in[16];
  const float* GLlin2_w= (const float*)d_in[17];
  float* out = (float*)d_out;

  ushort* U = (ushort*)d_ws;
  float* F = (float*)d_ws;
  const int M1U = 1048576;
  ushort* symP  = U + 0;            // (unused in R19)
  ushort* H0bf  = U + 16 * M1U;
  ushort* e2wbf = U + 17 * M1U;
  ushort* g1tbf = U + 18 * M1U;
  ushort* g2tbf = U + 19 * M1U;
  ushort* hTbf  = U + 20 * M1U;
  ushort* XAbf  = U + 21 * M1U;     // [b][e][n]
  ushort* XAT   = U + 22 * M1U;     // [b][n][e]
  ushort* g12T  = U + 23 * M1U;     // [n][k]
  ushort* gebf  = U + 24 * M1U;     // 2M  [b][n][128]
  ushort* y1b   = U + 26 * M1U;     // [b][e][n] bf16
  ushort* y2b   = U + 27 * M1U;
  ushort* w2bf  = U + 28 * M1U;     // 16K
  ushort* Acat  = U + 28 * M1U + 16384;
  ushort* glEbf = U + 28 * M1U + 32768;  // 64K
  // ushort region ends at 29,458,432 ushorts = 14,729,216 floats
  float* H02  = F + 14729216;
  float* SM   = F + 15777792;
  float* e1    = SM;
  float* e2    = SM + 16384;
  float* rsinv = SM + 32768;
  float* dd    = SM + 49152;   // 2048
  float* c1    = SM + 51200;
  float* c2    = SM + 52224;
  float* c12   = SM + 53248;
  float* lb2   = SM + 54272;   // 64 (pad)
  float* den   = SM + 54400;   // 16384
  float* part  = SM + 70784;   // 64

  // merged prep: lap rowsum | Acat/lb2/part0/glE/den0 | casts + embedding
  prep0_k<<<10658, 256, 0, stream>>>(
      graph, dd, lin1_w, lin2_w, lin2_b, lb2, Acat, GL, GLlin_w, glEbf,
      emb2_w, GLlin2_w, e2wbf, w2bf, x, emb_w, emb_b, H0bf, part, den);
  lap_fused_k<<<2048, 256, 0, stream>>>(graph, dd, g1tbf, g2tbf, c1, c2);
  lap_vec_k<<<1024, 256, 0, stream>>>(graph, dd, c1, c12, 1);

  // co-launched: H02 (z=0) || g12T (z=1)
  gg_k<<<dim3(16, 16, 2), 256, 0, stream>>>(
      H0bf, e2wbf, emb2_b, H02, g2tbf, g1tbf, g12T);

  // attention
  hmix_k<<<256, 256, 0, stream>>>(H02, att_W, att_a, hTbf, e1, e2);
  att_rowstats_k<<<Bn * Nn, 256, 0, stream>>>(e1, e2, rsinv);
  pxa_k<<<dim3(16, 16), 512, 0, stream>>>(hTbf, e1, e2, rsinv, XAbf, XAT);

  // learned graph: ge = [XAT|glE] @ W2^T ; den[m] = sum_k exp(relu(ge ge^T))
  mgemm_k<4, 0, 1><<<dim3(16, 2, 16), 256, 0, stream>>>(
      XAT, w2bf, glEbf, gebf, nullptr,
      nullptr, nullptr, nullptr, nullptr,
      128, 64, 128, 128, PB, 0, (long)Nn * 128);
  mgemm_k<6, 0, 0><<<dim3(16, 16, 16), 256, 0, stream>>>(
      gebf, gebf, nullptr, nullptr, nullptr,
      nullptr, nullptr, nullptr, den,
      128, 128, 128, 1024, (long)Nn * 128, (long)Nn * 128, NNc);

  // flash-style u/w + ymix (ST regenerated from ge, XCD-localized)
  fuw_k<<<dim3(16, 16), 256, 0, stream>>>(
      gebf, den, g12T, XAbf, XAT, Acat, lin2_b, lb2, c2, c12,
      y1b, y2b, part);

  // fused final (LN finish + gelu + cell update)
  final_k<<<BEN / 256, 256, 0, stream>>>(y1b, y2b, XAbf, ct, ln_w, ln_b,
                                         part, out);
}

// Round 20
// 138.100 us; speedup vs baseline: 1.0641x; 1.0637x over previous
//
#include <hip/hip_runtime.h>
#include <hip/hip_bf16.h>
#include <math.h>

constexpr int Bn  = 16;
constexpr int Nn  = 1024;
constexpr int CIN = 3;
constexpr int En  = 64;
constexpr int Gn  = 16;
constexpr int PB  = En * Nn;      // 65536
constexpr int BEN = Bn * PB;      // 1,048,576
constexpr int NNc = Nn * Nn;      // 1,048,576

typedef __attribute__((ext_vector_type(8))) short bf16x8;
typedef __attribute__((ext_vector_type(4))) float f32x4;

__device__ inline ushort f2b(float f) {
  union { __hip_bfloat16 h; ushort u; } v;
  v.h = __float2bfloat16(f);
  return v.u;
}
__device__ inline float b2f(ushort u) {
  union { ushort u; __hip_bfloat16 h; } v;
  v.u = u;
  return __bfloat162float(v.h);
}

// ---------------------------------------------------------------------------
// MFMA bf16 GEMM core: 64x64 tile, 4 waves, BK=64.
// ASPLIT: A = [XAT | glEbf]. EPI: 4 C16; 5 E=exp(relu(v)) -> C16 + den atomics.
// ---------------------------------------------------------------------------
template <int EPI, int BGEN, int ASPLIT>
__global__ __launch_bounds__(256) void mgemm_k(
    const ushort* __restrict__ A, const ushort* __restrict__ Bt,
    const ushort* __restrict__ A2,
    ushort* __restrict__ C16, ushort* __restrict__ C16b,
    const float* __restrict__ q1, const float* __restrict__ q2,
    const float* __restrict__ q4, float* __restrict__ dout,
    int K, int lda, int ldb, int ldc, long sA, long sB, long sC) {
  __shared__ ushort Al[5120];
  __shared__ ushort Bl[5120];
  int tid = threadIdx.x;
  int w = tid >> 6, l = tid & 63;
  int wm = (w >> 1) << 5, wn = (w & 1) << 5;
  int m0 = blockIdx.x << 6, n0 = blockIdx.y << 6, z = blockIdx.z;
  const ushort* Ab = A + (size_t)z * sA;
  const ushort* Bb = Bt + (size_t)z * sB;
  int r0 = tid >> 3, c0 = (tid & 7) << 3;
  int lo0 = (c0 >> 5) * 2560 + r0 * 40 + (c0 & 31);
  int lo1 = (c0 >> 5) * 2560 + (r0 + 32) * 40 + (c0 & 31);
  int fr = l & 15, fg = l >> 4;
  f32x4 acc[2][2] = {};

  int4 ra0, ra1, rb0, rb1;

  auto FETCH = [&](int k0) {
    if (ASPLIT) {
      const ushort* base = (k0 == 0) ? Ab : A2;
      ra0 = *(const int4*)(base + (size_t)(m0 + r0) * 64 + c0);
      ra1 = *(const int4*)(base + (size_t)(m0 + r0 + 32) * 64 + c0);
    } else {
      ra0 = *(const int4*)(Ab + (size_t)(m0 + r0) * lda + k0 + c0);
      ra1 = *(const int4*)(Ab + (size_t)(m0 + r0 + 32) * lda + k0 + c0);
    }
    rb0 = *(const int4*)(Bb + (size_t)(n0 + r0) * ldb + k0 + c0);
    rb1 = *(const int4*)(Bb + (size_t)(n0 + r0 + 32) * ldb + k0 + c0);
  };

  auto STORE = [&]() {
    *(int4*)&Al[lo0] = ra0;
    *(int4*)&Al[lo1] = ra1;
    *(int4*)&Bl[lo0] = rb0;
    *(int4*)&Bl[lo1] = rb1;
  };

  FETCH(0);
  for (int k0 = 0; k0 < K; k0 += 64) {
    __syncthreads();
    STORE();
    __syncthreads();
    if (k0 + 64 < K) FETCH(k0 + 64);
#pragma unroll
    for (int kk = 0; kk < 2; ++kk) {
      bf16x8 af[2], bfv[2];
#pragma unroll
      for (int i = 0; i < 2; ++i)
        af[i] = *(const bf16x8*)&Al[kk * 2560 + (wm + (i << 4) + fr) * 40 + (fg << 3)];
#pragma unroll
      for (int j = 0; j < 2; ++j)
        bfv[j] = *(const bf16x8*)&Bl[kk * 2560 + (wn + (j << 4) + fr) * 40 + (fg << 3)];
#pragma unroll
      for (int i = 0; i < 2; ++i)
#pragma unroll
        for (int j = 0; j < 2; ++j)
          acc[i][j] = __builtin_amdgcn_mfma_f32_16x16x32_bf16(
              af[i], bfv[j], acc[i][j], 0, 0, 0);
    }
  }

  int crb = (l >> 4) << 2, ccol = l & 15;
  if (EPI == 5) {
    float rp[8];
#pragma unroll
    for (int q = 0; q < 8; ++q) rp[q] = 0.f;
#pragma unroll
    for (int i = 0; i < 2; ++i)
#pragma unroll
      for (int j = 0; j < 2; ++j)
#pragma unroll
        for (int r = 0; r < 4; ++r) {
          int row = m0 + wm + (i << 4) + crb + r;
          int col = n0 + wn + (j << 4) + ccol;
          float v = fmaxf(acc[i][j][r], 0.f);
          float Ev = __expf(v);
          C16[(size_t)z * sC + (size_t)row * ldc + col] = f2b(Ev);
          rp[i * 4 + r] += Ev;
        }
    __syncthreads();
    float* rs = (float*)Al;
    if (tid < 64) rs[tid] = 0.f;
    __syncthreads();
#pragma unroll
    for (int i = 0; i < 2; ++i)
#pragma unroll
      for (int r = 0; r < 4; ++r) {
        float p = rp[i * 4 + r];
#pragma unroll
        for (int msk = 1; msk < 16; msk <<= 1) p += __shfl_xor(p, msk);
        if ((l & 15) == 0) atomicAdd(&rs[wm + (i << 4) + crb + r], p);
      }
    __syncthreads();
    if (tid < 64) atomicAdd(&dout[((size_t)z << 10) + m0 + tid], rs[tid]);
  } else {
#pragma unroll
    for (int i = 0; i < 2; ++i)
#pragma unroll
      for (int j = 0; j < 2; ++j)
#pragma unroll
        for (int r = 0; r < 4; ++r) {
          int row = m0 + wm + (i << 4) + crb + r;
          int col = n0 + wn + (j << 4) + ccol;
          size_t off = (size_t)z * sC + (size_t)row * ldc + col;
          if (EPI == 4) C16[off] = f2b(acc[i][j][r]);
        }
  }
}

// ---------------------------------------------------------------------------
// pxa_k: split-K wave-groups + depth-2 pipeline.
// P generated in staging; out: XAbf [b][e][n] = relu(P@h), XAT [b][n][e].
// ---------------------------------------------------------------------------
__global__ __launch_bounds__(512) void pxa_k(
    const ushort* __restrict__ hT, const float* __restrict__ e1,
    const float* __restrict__ e2, const float* __restrict__ rsinv,
    ushort* __restrict__ XAbf, ushort* __restrict__ XAT) {
  __shared__ ushort Al[2][5120];
  __shared__ ushort Bl[2][5120];
  __shared__ float cmb[256 * 16];
  int tid = threadIdx.x;
  int grp = tid >> 8;
  int t = tid & 255;
  int w = t >> 6, l = t & 63;
  int wm = (w >> 1) << 5, wn = (w & 1) << 5;
  int n0 = blockIdx.x << 6, z = blockIdx.y;
  int kbase = grp << 9;
  const ushort* Ab = hT + (size_t)z * PB;
  int r0 = t >> 3, c0 = (t & 7) << 3;
  int lo0 = (c0 >> 5) * 2560 + r0 * 40 + (c0 & 31);
  int lo1 = (c0 >> 5) * 2560 + (r0 + 32) * 40 + (c0 & 31);
  int fr = l & 15, fg = l >> 4;
  f32x4 acc[2][2] = {};

  const float* e1b = e1 + (z << 10);
  const float* rsb = rsinv + (z << 10);
  float ei0 = e1b[n0 + r0], sc0 = rsb[n0 + r0];
  float ei1 = e1b[n0 + r0 + 32], sc1 = rsb[n0 + r0 + 32];

  int4 raA0, raA1, raB0, raB1;
  float fA[8], fB[8];

  auto FETCHA = [&](int k0) {
    raA0 = *(const int4*)(Ab + (size_t)r0 * 1024 + k0 + c0);
    raA1 = *(const int4*)(Ab + (size_t)(r0 + 32) * 1024 + k0 + c0);
    const float* e2b = e2 + (z << 10) + k0 + c0;
    *(float4*)&fA[0] = *(const float4*)(e2b);
    *(float4*)&fA[4] = *(const float4*)(e2b + 4);
  };
  auto FETCHB = [&](int k0) {
    raB0 = *(const int4*)(Ab + (size_t)r0 * 1024 + k0 + c0);
    raB1 = *(const int4*)(Ab + (size_t)(r0 + 32) * 1024 + k0 + c0);
    const float* e2b = e2 + (z << 10) + k0 + c0;
    *(float4*)&fB[0] = *(const float4*)(e2b);
    *(float4*)&fB[4] = *(const float4*)(e2b + 4);
  };
  auto STOREA = [&]() {
    *(int4*)&Al[grp][lo0] = raA0;
    *(int4*)&Al[grp][lo1] = raA1;
    ushort o0[8], o1[8];
#pragma unroll
    for (int q = 0; q < 8; ++q) {
      float z0 = ei0 + fA[q];
      z0 = z0 >= 0.f ? z0 : 0.01f * z0;
      o0[q] = f2b(__expf(z0) * sc0);
      float z1 = ei1 + fA[q];
      z1 = z1 >= 0.f ? z1 : 0.01f * z1;
      o1[q] = f2b(__expf(z1) * sc1);
    }
    *(int4*)&Bl[grp][lo0] = *(int4*)o0;
    *(int4*)&Bl[grp][lo1] = *(int4*)o1;
  };
  auto STOREB = [&]() {
    *(int4*)&Al[grp][lo0] = raB0;
    *(int4*)&Al[grp][lo1] = raB1;
    ushort o0[8], o1[8];
#pragma unroll
    for (int q = 0; q < 8; ++q) {
      float z0 = ei0 + fB[q];
      z0 = z0 >= 0.f ? z0 : 0.01f * z0;
      o0[q] = f2b(__expf(z0) * sc0);
      float z1 = ei1 + fB[q];
      z1 = z1 >= 0.f ? z1 : 0.01f * z1;
      o1[q] = f2b(__expf(z1) * sc1);
    }
    *(int4*)&Bl[grp][lo0] = *(int4*)o0;
    *(int4*)&Bl[grp][lo1] = *(int4*)o1;
  };
  auto MFMAS = [&]() {
#pragma unroll
    for (int kk = 0; kk < 2; ++kk) {
      bf16x8 af[2], bfv[2];
#pragma unroll
      for (int i = 0; i < 2; ++i)
        af[i] = *(const bf16x8*)&Al[grp][kk * 2560 + (wm + (i << 4) + fr) * 40 + (fg << 3)];
#pragma unroll
      for (int j = 0; j < 2; ++j)
        bfv[j] = *(const bf16x8*)&Bl[grp][kk * 2560 + (wn + (j << 4) + fr) * 40 + (fg << 3)];
#pragma unroll
      for (int i = 0; i < 2; ++i)
#pragma unroll
        for (int j = 0; j < 2; ++j)
          acc[i][j] = __builtin_amdgcn_mfma_f32_16x16x32_bf16(
              af[i], bfv[j], acc[i][j], 0, 0, 0);
    }
  };

  FETCHA(kbase);
  FETCHB(kbase + 64);
  for (int ks = 0; ks < 8; ks += 2) {
    __syncthreads();
    STOREA();
    __syncthreads();
    if (ks + 2 < 8) FETCHA(kbase + ((ks + 2) << 6));
    MFMAS();
    __syncthreads();
    STOREB();
    __syncthreads();
    if (ks + 3 < 8) FETCHB(kbase + ((ks + 3) << 6));
    MFMAS();
  }

  __syncthreads();
  if (grp == 1) {
    float* d = cmb + t * 16;
#pragma unroll
    for (int i = 0; i < 2; ++i)
#pragma unroll
      for (int j = 0; j < 2; ++j)
#pragma unroll
        for (int r = 0; r < 4; ++r) d[((i << 1) + j) * 4 + r] = acc[i][j][r];
  }
  __syncthreads();
  if (grp == 1) return;
  const float* s = cmb + t * 16;
#pragma unroll
  for (int i = 0; i < 2; ++i)
#pragma unroll
    for (int j = 0; j < 2; ++j)
#pragma unroll
      for (int r = 0; r < 4; ++r) acc[i][j][r] += s[((i << 1) + j) * 4 + r];

  int crb = (l >> 4) << 2, ccol = l & 15;
#pragma unroll
  for (int i = 0; i < 2; ++i)
#pragma unroll
    for (int j = 0; j < 2; ++j)
#pragma unroll
      for (int r = 0; r < 4; ++r) {
        int row = wm + (i << 4) + crb + r;        // e index
        int col = n0 + wn + (j << 4) + ccol;      // node index
        float v = fmaxf(acc[i][j][r], 0.f);
        XAbf[(size_t)z * PB + (size_t)row * 1024 + col] = f2b(v);
        XAT[(size_t)z * PB + (size_t)col * 64 + row] = f2b(v);
      }
}

// ---------------------------------------------------------------------------
// gg_k (depth-2), grid (16,16,2).
// z=0: H02 = H0 @ emb2_w^T + emb2_b (fp32); z=1: g12T = g2t @ g1t (bf16).
// ---------------------------------------------------------------------------
__global__ __launch_bounds__(256) void gg_k(
    const ushort* __restrict__ H0bf, const ushort* __restrict__ e2wbf,
    const float* __restrict__ emb2b, float* __restrict__ H02,
    const ushort* __restrict__ g2t, const ushort* __restrict__ g1t,
    ushort* __restrict__ g12T) {
  __shared__ ushort Al[5120];
  __shared__ ushort Bl[5120];
  int tid = threadIdx.x;
  int w = tid >> 6, l = tid & 63;
  int wm = (w >> 1) << 5, wn = (w & 1) << 5;
  int m0 = blockIdx.x << 6, n0 = blockIdx.y << 6;
  int job = blockIdx.z;
  const ushort* Ab = job ? g2t : H0bf;
  int r0 = tid >> 3, c0 = (tid & 7) << 3;
  int lo0 = (c0 >> 5) * 2560 + r0 * 40 + (c0 & 31);
  int lo1 = (c0 >> 5) * 2560 + (r0 + 32) * 40 + (c0 & 31);
  int fr = l & 15, fg = l >> 4;
  f32x4 acc[2][2] = {};
  int4 raA0, raA1, rbA0, rbA1;
  int4 raB0, raB1, rbB0, rbB1;

  auto FETCHA = [&](int k0) {
    raA0 = *(const int4*)(Ab + (size_t)(m0 + r0) * 1024 + k0 + c0);
    raA1 = *(const int4*)(Ab + (size_t)(m0 + r0 + 32) * 1024 + k0 + c0);
    if (job) {
      rbA0 = *(const int4*)(g1t + (size_t)(k0 + r0) * 1024 + n0 + c0);
      rbA1 = *(const int4*)(g1t + (size_t)(k0 + r0 + 32) * 1024 + n0 + c0);
    } else {
      rbA0 = *(const int4*)(e2wbf + (size_t)(n0 + r0) * 1024 + k0 + c0);
      rbA1 = *(const int4*)(e2wbf + (size_t)(n0 + r0 + 32) * 1024 + k0 + c0);
    }
  };
  auto FETCHB = [&](int k0) {
    raB0 = *(const int4*)(Ab + (size_t)(m0 + r0) * 1024 + k0 + c0);
    raB1 = *(const int4*)(Ab + (size_t)(m0 + r0 + 32) * 1024 + k0 + c0);
    if (job) {
      rbB0 = *(const int4*)(g1t + (size_t)(k0 + r0) * 1024 + n0 + c0);
      rbB1 = *(const int4*)(g1t + (size_t)(k0 + r0 + 32) * 1024 + n0 + c0);
    } else {
      rbB0 = *(const int4*)(e2wbf + (size_t)(n0 + r0) * 1024 + k0 + c0);
      rbB1 = *(const int4*)(e2wbf + (size_t)(n0 + r0 + 32) * 1024 + k0 + c0);
    }
  };
  auto STOREA = [&]() {
    *(int4*)&Al[lo0] = raA0;
    *(int4*)&Al[lo1] = raA1;
    if (job) {
      const ushort* p0 = (const ushort*)&rbA0;
      const ushort* p1 = (const ushort*)&rbA1;
#pragma unroll
      for (int q = 0; q < 8; ++q) {
        Bl[(c0 + q) * 40 + r0] = p0[q];
        Bl[2560 + (c0 + q) * 40 + r0] = p1[q];
      }
    } else {
      *(int4*)&Bl[lo0] = rbA0;
      *(int4*)&Bl[lo1] = rbA1;
    }
  };
  auto STOREB = [&]() {
    *(int4*)&Al[lo0] = raB0;
    *(int4*)&Al[lo1] = raB1;
    if (job) {
      const ushort* p0 = (const ushort*)&rbB0;
      const ushort* p1 = (const ushort*)&rbB1;
#pragma unroll
      for (int q = 0; q < 8; ++q) {
        Bl[(c0 + q) * 40 + r0] = p0[q];
        Bl[2560 + (c0 + q) * 40 + r0] = p1[q];
      }
    } else {
      *(int4*)&Bl[lo0] = rbB0;
      *(int4*)&Bl[lo1] = rbB1;
    }
  };
  auto MFMAS = [&]() {
#pragma unroll
    for (int kk = 0; kk < 2; ++kk) {
      bf16x8 af[2], bfv[2];
#pragma unroll
      for (int i = 0; i < 2; ++i)
        af[i] = *(const bf16x8*)&Al[kk * 2560 + (wm + (i << 4) + fr) * 40 + (fg << 3)];
#pragma unroll
      for (int j = 0; j < 2; ++j)
        bfv[j] = *(const bf16x8*)&Bl[kk * 2560 + (wn + (j << 4) + fr) * 40 + (fg << 3)];
#pragma unroll
      for (int i = 0; i < 2; ++i)
#pragma unroll
        for (int j = 0; j < 2; ++j)
          acc[i][j] = __builtin_amdgcn_mfma_f32_16x16x32_bf16(
              af[i], bfv[j], acc[i][j], 0, 0, 0);
    }
  };

  FETCHA(0);
  FETCHB(64);
  for (int ks = 0; ks < 16; ks += 2) {
    __syncthreads();
    STOREA();
    __syncthreads();
    if (ks + 2 < 16) FETCHA((ks + 2) << 6);
    MFMAS();
    __syncthreads();
    STOREB();
    __syncthreads();
    if (ks + 3 < 16) FETCHB((ks + 3) << 6);
    MFMAS();
  }

  int crb = (l >> 4) << 2, ccol = l & 15;
#pragma unroll
  for (int i = 0; i < 2; ++i)
#pragma unroll
    for (int j = 0; j < 2; ++j)
#pragma unroll
      for (int r = 0; r < 4; ++r) {
        int row = m0 + wm + (i << 4) + crb + r;
        int col = n0 + wn + (j << 4) + ccol;
        float v = acc[i][j][r];
        if (job) g12T[(size_t)row * 1024 + col] = f2b(v);
        else H02[(size_t)row * 1024 + col] = v + emb2b[col];
      }
}

// ---------------------------------------------------------------------------
// uwymix_k (split-K wave-groups + depth-2 named-set pipeline).
// u = ST@XA + xa^T, w = g12@XA, then y1/y2 = Acat@[u;w] + rank1 + LN atomics.
// ---------------------------------------------------------------------------
__global__ __launch_bounds__(512) void uwymix_k(
    const ushort* __restrict__ E, const float* __restrict__ den,
    const ushort* __restrict__ g12T, const ushort* __restrict__ XAbf,
    const ushort* __restrict__ XAT, const ushort* __restrict__ Acat,
    const float* __restrict__ b2, const float* __restrict__ lb2,
    const float* __restrict__ c2, const float* __restrict__ c12,
    ushort* __restrict__ y1, ushort* __restrict__ y2,
    float* __restrict__ part) {
  __shared__ ushort Au[2][5120];
  __shared__ ushort Ag[2][5120];
  __shared__ ushort Bx[2][5120];
  __shared__ ushort UW[64 * 132];
  __shared__ float colS[64];
  __shared__ float cmb[256 * 18];
  int tid = threadIdx.x;
  int grp = tid >> 8;
  int t = tid & 255;
  int w = t >> 6, l = t & 63;
  int wm = (w >> 1) << 5, wn = (w & 1) << 5;
  int m0 = blockIdx.x << 6, z = blockIdx.y;
  int kbase = grp << 9;
  const ushort* Bb = XAbf + (size_t)z * PB;
  int r0 = t >> 3, c0 = (t & 7) << 3;
  int lo0 = (c0 >> 5) * 2560 + r0 * 40 + (c0 & 31);
  int lo1 = (c0 >> 5) * 2560 + (r0 + 32) * 40 + (c0 & 31);
  int fr = l & 15, fg = l >> 4;
  f32x4 au[2][2] = {};
  f32x4 aw[2][2] = {};
  float cs0 = 0.f, cs1 = 0.f;
  const ushort* Es0 = E + (size_t)z * NNc + (size_t)(m0 + r0) * 1024;
  const ushort* Es1 = Es0 + 32 * 1024;
  const ushort* Gs0 = g12T + (size_t)(m0 + r0) * 1024;
  const ushort* Gs1 = Gs0 + 32 * 1024;
  const float* dnb = den + (z << 10);

  int4 rsA0, rsA1, rgA0, rgA1, rbA0, rbA1;
  float fA[8];
  int4 rsB0, rsB1, rgB0, rgB1, rbB0, rbB1;
  float fB[8];

  auto FETCHA = [&](int k0) {
    rsA0 = *(const int4*)(Es0 + k0 + c0);
    rsA1 = *(const int4*)(Es1 + k0 + c0);
    rgA0 = *(const int4*)(Gs0 + k0 + c0);
    rgA1 = *(const int4*)(Gs1 + k0 + c0);
    rbA0 = *(const int4*)(Bb + (size_t)r0 * 1024 + k0 + c0);
    rbA1 = *(const int4*)(Bb + (size_t)(r0 + 32) * 1024 + k0 + c0);
    *(float4*)&fA[0] = *(const float4*)(dnb + k0 + c0);
    *(float4*)&fA[4] = *(const float4*)(dnb + k0 + c0 + 4);
  };
  auto FETCHB = [&](int k0) {
    rsB0 = *(const int4*)(Es0 + k0 + c0);
    rsB1 = *(const int4*)(Es1 + k0 + c0);
    rgB0 = *(const int4*)(Gs0 + k0 + c0);
    rgB1 = *(const int4*)(Gs1 + k0 + c0);
    rbB0 = *(const int4*)(Bb + (size_t)r0 * 1024 + k0 + c0);
    rbB1 = *(const int4*)(Bb + (size_t)(r0 + 32) * 1024 + k0 + c0);
    *(float4*)&fB[0] = *(const float4*)(dnb + k0 + c0);
    *(float4*)&fB[4] = *(const float4*)(dnb + k0 + c0 + 4);
  };
  auto STOREA = [&]() {
    *(int4*)&Ag[grp][lo0] = rgA0;
    *(int4*)&Ag[grp][lo1] = rgA1;
    *(int4*)&Bx[grp][lo0] = rbA0;
    *(int4*)&Bx[grp][lo1] = rbA1;
    ushort o0[8], o1[8];
    const ushort* p0 = (const ushort*)&rsA0;
    const ushort* p1 = (const ushort*)&rsA1;
#pragma unroll
    for (int q = 0; q < 8; ++q) {
      float rcp = __builtin_amdgcn_rcpf(fA[q]);
      float v0 = b2f(p0[q]) * rcp;
      o0[q] = f2b(v0);
      cs0 += v0;
      float v1 = b2f(p1[q]) * rcp;
      o1[q] = f2b(v1);
      cs1 += v1;
    }
    *(int4*)&Au[grp][lo0] = *(int4*)o0;
    *(int4*)&Au[grp][lo1] = *(int4*)o1;
  };
  auto STOREB = [&]() {
    *(int4*)&Ag[grp][lo0] = rgB0;
    *(int4*)&Ag[grp][lo1] = rgB1;
    *(int4*)&Bx[grp][lo0] = rbB0;
    *(int4*)&Bx[grp][lo1] = rbB1;
    ushort o0[8], o1[8];
    const ushort* p0 = (const ushort*)&rsB0;
    const ushort* p1 = (const ushort*)&rsB1;
#pragma unroll
    for (int q = 0; q < 8; ++q) {
      float rcp = __builtin_amdgcn_rcpf(fB[q]);
      float v0 = b2f(p0[q]) * rcp;
      o0[q] = f2b(v0);
      cs0 += v0;
      float v1 = b2f(p1[q]) * rcp;
      o1[q] = f2b(v1);
      cs1 += v1;
    }
    *(int4*)&Au[grp][lo0] = *(int4*)o0;
    *(int4*)&Au[grp][lo1] = *(int4*)o1;
  };
  auto MFMAS = [&]() {
#pragma unroll
    for (int kk = 0; kk < 2; ++kk) {
      bf16x8 fu[2], fw[2], fb[2];
#pragma unroll
      for (int i = 0; i < 2; ++i) {
        int off = kk * 2560 + (wm + (i << 4) + fr) * 40 + (fg << 3);
        fu[i] = *(const bf16x8*)&Au[grp][off];
        fw[i] = *(const bf16x8*)&Ag[grp][off];
      }
#pragma unroll
      for (int j = 0; j < 2; ++j)
        fb[j] = *(const bf16x8*)&Bx[grp][kk * 2560 + (wn + (j << 4) + fr) * 40 + (fg << 3)];
#pragma unroll
      for (int i = 0; i < 2; ++i)
#pragma unroll
        for (int j = 0; j < 2; ++j) {
          au[i][j] = __builtin_amdgcn_mfma_f32_16x16x32_bf16(
              fu[i], fb[j], au[i][j], 0, 0, 0);
          aw[i][j] = __builtin_amdgcn_mfma_f32_16x16x32_bf16(
              fw[i], fb[j], aw[i][j], 0, 0, 0);
        }
    }
  };

  FETCHA(kbase);
  FETCHB(kbase + 64);
  for (int ks = 0; ks < 8; ks += 2) {
    __syncthreads();
    STOREA();
    __syncthreads();
    if (ks + 2 < 8) FETCHA(kbase + ((ks + 2) << 6));
    MFMAS();
    __syncthreads();
    STOREB();
    __syncthreads();
    if (ks + 3 < 8) FETCHB(kbase + ((ks + 3) << 6));
    MFMAS();
  }

  // combine group-1 partials into group 0 (two passes through cmb)
  __syncthreads();
  if (grp == 1) {
    float* d = cmb + t * 18;
#pragma unroll
    for (int i = 0; i < 2; ++i)
#pragma unroll
      for (int j = 0; j < 2; ++j)
#pragma unroll
        for (int r = 0; r < 4; ++r) d[((i << 1) + j) * 4 + r] = au[i][j][r];
    d[16] = cs0;
    d[17] = cs1;
  }
  __syncthreads();
  if (grp == 0) {
    const float* s = cmb + t * 18;
#pragma unroll
    for (int i = 0; i < 2; ++i)
#pragma unroll
      for (int j = 0; j < 2; ++j)
#pragma unroll
        for (int r = 0; r < 4; ++r) au[i][j][r] += s[((i << 1) + j) * 4 + r];
    cs0 += s[16];
    cs1 += s[17];
  }
  __syncthreads();
  if (grp == 1) {
    float* d = cmb + t * 18;
#pragma unroll
    for (int i = 0; i < 2; ++i)
#pragma unroll
      for (int j = 0; j < 2; ++j)
#pragma unroll
        for (int r = 0; r < 4; ++r) d[((i << 1) + j) * 4 + r] = aw[i][j][r];
  }
  __syncthreads();
  int crb = (l >> 4) << 2, ccol = l & 15;
  if (grp == 0) {
    const float* s = cmb + t * 18;
#pragma unroll
    for (int i = 0; i < 2; ++i)
#pragma unroll
      for (int j = 0; j < 2; ++j)
#pragma unroll
        for (int r = 0; r < 4; ++r) aw[i][j][r] += s[((i << 1) + j) * 4 + r];
#pragma unroll
    for (int msk = 1; msk < 8; msk <<= 1) {
      cs0 += __shfl_xor(cs0, msk);
      cs1 += __shfl_xor(cs1, msk);
    }
    if ((t & 7) == 0) {
      colS[r0] = cs0;
      colS[r0 + 32] = cs1;
    }
#pragma unroll
    for (int i = 0; i < 2; ++i)
#pragma unroll
      for (int j = 0; j < 2; ++j)
#pragma unroll
        for (int r = 0; r < 4; ++r) {
          int node = wm + (i << 4) + crb + r;
          int e = wn + (j << 4) + ccol;
          float uv = au[i][j][r] +
                     b2f(XAT[(size_t)z * PB + (size_t)(m0 + node) * 64 + e]);
          UW[node * 132 + e] = f2b(uv);
          UW[node * 132 + 64 + e] = f2b(aw[i][j][r]);
        }
  }
  __syncthreads();
  if (grp == 1) return;

  // phase C: y = Acat @ [u;w] (K=128). waves 0,1 -> y1; 2,3 -> y2.
  int half = w >> 1;
  int mrow = (w & 1) << 5;
  const ushort* Ac = Acat + half * 8192;
  bf16x8 af[2][4];
#pragma unroll
  for (int i = 0; i < 2; ++i)
#pragma unroll
    for (int s = 0; s < 4; ++s)
      af[i][s] = *(const bf16x8*)&Ac[(mrow + i * 16 + fr) * 128 + s * 32 + fg * 8];
  f32x4 acc[2][4] = {};
#pragma unroll
  for (int s = 0; s < 4; ++s) {
    bf16x8 bv[4];
#pragma unroll
    for (int j = 0; j < 4; ++j)
      bv[j] = *(const bf16x8*)&UW[(j * 16 + fr) * 132 + s * 32 + fg * 8];
#pragma unroll
    for (int i = 0; i < 2; ++i)
#pragma unroll
      for (int j = 0; j < 4; ++j)
        acc[i][j] = __builtin_amdgcn_mfma_f32_16x16x32_bf16(
            af[i][s], bv[j], acc[i][j], 0, 0, 0);
  }
  ushort* Y = half ? y2 : y1;
  float ysum = 0.f, yss = 0.f;
#pragma unroll
  for (int i = 0; i < 2; ++i)
#pragma unroll
    for (int j = 0; j < 4; ++j) {
      int node = (j << 4) + ccol;
      float rk = 0.f, r12 = 0.f;
      if (half) {
        rk = 1.0f + colS[node] + c2[m0 + node];
        r12 = c12[m0 + node];
      }
#pragma unroll
      for (int r = 0; r < 4; ++r) {
        int row = mrow + (i << 4) + crb + r;
        float v = acc[i][j][r];
        if (half) v += b2[row] * rk + lb2[row] * r12;
        Y[(size_t)z * PB + (size_t)row * 1024 + m0 + node] = f2b(v);
        ysum += v;
        yss = fmaf(v, v, yss);
      }
    }
#pragma unroll
  for (int msk = 1; msk < 64; msk <<= 1) {
    ysum += __shfl_xor(ysum, msk);
    yss += __shfl_xor(yss, msk);
  }
  if (l == 0) {
    atomicAdd(&part[half * 32 + z * 2], ysum);
    atomicAdd(&part[half * 32 + z * 2 + 1], yss);
  }
}

// ---------------------------------------------------------------------------
// prep0_k: [0,2048) lap rowsum; [2048,2402) Acat/lb2/part0/glE/den0;
// [2402,10658) weight casts + embedding.
// ---------------------------------------------------------------------------
__global__ __launch_bounds__(256) void prep0_k(
    const float* __restrict__ graph, float* __restrict__ dd,
    const float* __restrict__ L1, const float* __restrict__ L2,
    const float* __restrict__ b2, float* __restrict__ lb2,
    ushort* __restrict__ Acat, const float* __restrict__ GL,
    const float* __restrict__ GLlin_w, ushort* __restrict__ glEbf,
    const float* __restrict__ emb2w, const float* __restrict__ w2,
    ushort* __restrict__ e2wbf, ushort* __restrict__ w2bf,
    const float* __restrict__ x, const float* __restrict__ emb_w,
    const float* __restrict__ emb_b, ushort* __restrict__ H0,
    float* __restrict__ part, float* __restrict__ den) {
  int blk = blockIdx.x, tid = threadIdx.x;
  if (blk < 2048) {
    const float* row = graph + (size_t)blk * Nn;
    float s = 0.0f;
    for (int j = tid; j < Nn; j += 256) s += row[j];
    __shared__ float red[256];
    red[tid] = s;
    __syncthreads();
    for (int st = 128; st > 0; st >>= 1) {
      if (tid < st) red[tid] += red[tid + st];
      __syncthreads();
    }
    if (tid == 0) {
      float t = red[0] + 1.0f;
      dd[blk] = (t > 0.0f) ? rsqrtf(t) : 0.0f;
    }
  } else if (blk < 2402) {
    int pblk = blk - 2048;
    if (pblk < 32) {
      int mat = pblk >> 4;
      int o = ((pblk & 15) << 8) + tid;
      int e = o >> 6, c = o & 63;
      const float* L = mat ? L2 : L1;
      float s = 0.f;
#pragma unroll
      for (int t = 0; t < 64; ++t) s = fmaf(L[e * 64 + t], L[t * 64 + c], s);
      Acat[mat * 8192 + e * 128 + 64 + c] = f2b(s);
    } else if (pblk == 32) {
      for (int t = tid; t < 8192; t += 256) {
        int w = t >> 12, rem = t & 4095, m = rem >> 6, k = rem & 63;
        Acat[w * 8192 + m * 128 + k] = f2b((w ? L2 : L1)[m * 64 + k]);
      }
    } else if (pblk == 33) {
      if (tid < 64) {
        float s = 0.f;
#pragma unroll
        for (int c = 0; c < 64; ++c) s = fmaf(L2[tid * 64 + c], b2[c], s);
        lb2[tid] = s;
      } else if (tid < 128) {
        part[tid - 64] = 0.f;
      }
    } else if (pblk < 290) {
      int idx = (pblk - 34) * 256 + tid;  // < 65536
      int n = idx >> 6, e = idx & 63;
      float s = 0.0f;
#pragma unroll
      for (int g = 0; g < Gn; ++g)
        s = fmaf(GL[n * Gn + g], GLlin_w[e * Gn + g], s);
      glEbf[idx] = f2b(s);
    } else {
      int idx = (pblk - 290) * 256 + tid;  // < 16384
      den[idx] = 0.f;
    }
  } else {
    int cblk = blk - 2402;
    if (cblk < 4160) {
      int idx = cblk * 256 + tid;
      if (idx < NNc) e2wbf[idx] = f2b(emb2w[idx]);
      else if (idx < NNc + 16384) w2bf[idx - NNc] = f2b(w2[idx - NNc]);
    } else {
      int idx = (cblk - 4160) * 256 + tid;  // < BEN
      int b = idx >> 16, r = idx & 65535, e = r >> 10, n = r & 1023;
      const float* xb = x + (size_t)b * (CIN * Nn);
      float s = emb_b[e] + emb_w[e * 3 + 0] * xb[n] +
                emb_w[e * 3 + 1] * xb[Nn + n] +
                emb_w[e * 3 + 2] * xb[2 * Nn + n];
      s = s >= 0.0f ? s : 0.01f * s;
      H0[idx] = f2b(s);
    }
  }
}

// One pass over graph row (g,m): write g_t row m (bf16) + c_g[m].
__global__ __launch_bounds__(256) void lap_fused_k(
    const float* __restrict__ graph, const float* __restrict__ dd,
    ushort* __restrict__ g1t, ushort* __restrict__ g2t,
    float* __restrict__ c1, float* __restrict__ c2) {
  int gi = blockIdx.x;
  int g = gi >> 10, m = gi & 1023;
  const float* grow = graph + (size_t)gi * Nn;
  const float* ddg = dd + (g << 10);
  float ddm = ddg[m];
  ushort* gt = (g ? g2t : g1t) + (size_t)m * Nn;
  int tid = threadIdx.x;
  float s = 0.0f;
  for (int n = tid; n < Nn; n += 256) {
    float t = ddg[n] * grow[n];
    s += t;
    float v = t * ddm + (n == m ? ddm * ddm : 0.f);
    gt[n] = f2b(v);
  }
  __shared__ float red[256];
  red[tid] = s;
  __syncthreads();
  for (int st = 128; st > 0; st >>= 1) {
    if (tid < st) red[tid] += red[tid + st];
    __syncthreads();
  }
  if (tid == 0) (g ? c2 : c1)[m] = ddm * (red[0] + ddm);
}

// out[m] = lap-column action with vector vin (for c12)
__global__ __launch_bounds__(256) void lap_vec_k(
    const float* __restrict__ graph, const float* __restrict__ dd,
    const float* __restrict__ vin, float* __restrict__ out, int g) {
  int m = blockIdx.x;
  int tid = threadIdx.x;
  const float* grow = graph + (size_t)g * NNc + (size_t)m * Nn;
  const float* ddg = dd + (g << 10);
  float s = 0.0f;
  for (int n = tid; n < Nn; n += 256) s += ddg[n] * grow[n] * vin[n];
  __shared__ float red[256];
  red[tid] = s;
  __syncthreads();
  for (int st = 128; st > 0; st >>= 1) {
    if (tid < st) red[tid] += red[tid + st];
    __syncthreads();
  }
  if (tid == 0) out[m] = ddg[m] * (red[0] + ddg[m] * vin[m]);
}

// hT = attW-mix of H02; e1/e2 dots with att_a
__global__ __launch_bounds__(256) void hmix_k(
    const float* __restrict__ H02, const float* __restrict__ attW,
    const float* __restrict__ atta, ushort* __restrict__ hT,
    float* __restrict__ e1, float* __restrict__ e2) {
  __shared__ float Hs[64][65];
  __shared__ float pr1[4][64];
  __shared__ float pr2[4][64];
  int tid = threadIdx.x;
  int blk = blockIdx.x;
  int b = blk >> 4, n0 = (blk & 15) << 6;
  for (int t = tid; t < 4096; t += 256) {
    int e = t >> 6, n = t & 63;
    Hs[e][n] = H02[(size_t)(b * 64 + e) * 1024 + n0 + n];
  }
  __syncthreads();
  int n = tid & 63, epg = tid >> 6;
  float h[16];
#pragma unroll
  for (int i = 0; i < 16; ++i) h[i] = 0.f;
  for (int e = 0; e < 64; ++e) {
    float xv = Hs[e][n];
#pragma unroll
    for (int i = 0; i < 16; ++i)
      h[i] = fmaf(xv, attW[e * 64 + epg * 16 + i], h[i]);
  }
  float s1 = 0.f, s2 = 0.f;
#pragma unroll
  for (int i = 0; i < 16; ++i) {
    int ep = epg * 16 + i;
    hT[(size_t)(b * 64 + ep) * 1024 + n0 + n] = f2b(h[i]);
    s1 = fmaf(h[i], atta[ep], s1);
    s2 = fmaf(h[i], atta[64 + ep], s2);
  }
  pr1[epg][n] = s1;
  pr2[epg][n] = s2;
  __syncthreads();
  if (epg == 0) {
    e1[(b << 10) + n0 + n] = pr1[0][n] + pr1[1][n] + pr1[2][n] + pr1[3][n];
    e2[(b << 10) + n0 + n] = pr2[0][n] + pr2[1][n] + pr2[2][n] + pr2[3][n];
  }
}

// rsinv[i] = 1 / sum_j exp(lrelu(e1_i + e2_j))   (no-max softmax)
__global__ __launch_bounds__(256) void att_rowstats_k(
    const float* __restrict__ e1, const float* __restrict__ e2,
    float* __restrict__ rsinv) {
  int row = blockIdx.x;
  int b = row >> 10;
  const float* e2b = e2 + (b << 10);
  float a = e1[row];
  int tid = threadIdx.x;
  float sm = 0.0f;
#pragma unroll
  for (int l = 0; l < 4; ++l) {
    float v = a + e2b[tid + (l << 8)];
    v = v >= 0.0f ? v : 0.01f * v;
    sm += __expf(v);
  }
  __shared__ float red[256];
  red[tid] = sm;
  __syncthreads();
  for (int s = 128; s > 0; s >>= 1) {
    if (tid < s) red[tid] += red[tid + s];
    __syncthreads();
  }
  if (tid == 0) rsinv[row] = 1.0f / red[0];
}

// final: LN finish + affine + gelu + cell update (y1/y2 bf16)
__global__ __launch_bounds__(256) void final_k(
    const ushort* __restrict__ y1, const ushort* __restrict__ y2,
    const ushort* __restrict__ xabf, const float* __restrict__ ct,
    const float* __restrict__ ln_w, const float* __restrict__ ln_b,
    const float* __restrict__ part, float* __restrict__ out) {
  __shared__ float st[4];
  int idx = blockIdx.x * 256 + threadIdx.x;
  int b = idx >> 16, r = idx & 65535;
  if (threadIdx.x < 2) {
    int wq = threadIdx.x;
    float s = part[wq * 32 + b * 2];
    float ss = part[wq * 32 + b * 2 + 1];
    float mean = s * (1.0f / PB);
    float var = fmaxf(ss * (1.0f / PB) - mean * mean, 0.0f);
    st[wq * 2] = mean;
    st[wq * 2 + 1] = rsqrtf(var + 1e-5f);
  }
  __syncthreads();
  float m1 = st[0], s1 = st[1], m2 = st[2], s2 = st[3];
  float w = ln_w[r], bb = ln_b[r];
  float xn = (b2f(y1[idx]) - m1) * s1 * w + bb;
  float yg = (b2f(y2[idx]) - m2) * s2 * w + bb;
  float g = 0.5f * yg * (1.0f + erff(yg * 0.70710678118654752f));
  float c = ct[idx];
  float cn = xn + g * (c - xn);
  float el = cn > 0.0f ? cn : expm1f(cn);
  float xv = b2f(xabf[idx]);
  out[idx] = xv + g * (el - xv);
  out[BEN + idx] = cn;
}

extern "C" void kernel_launch(void* const* d_in, const int* in_sizes, int n_in,
                              void* d_out, int out_size, void* d_ws,
                              size_t ws_size, hipStream_t stream) {
  const float* x       = (const float*)d_in[0];
  const float* ct      = (const float*)d_in[1];
  const float* graph   = (const float*)d_in[2];
  const float* emb_w   = (const float*)d_in[3];
  const float* emb_b   = (const float*)d_in[4];
  const float* emb2_w  = (const float*)d_in[5];
  const float* emb2_b  = (const float*)d_in[6];
  const float* att_W   = (const float*)d_in[7];
  const float* att_a   = (const float*)d_in[8];
  const float* lin1_w  = (const float*)d_in[10];
  const float* lin2_w  = (const float*)d_in[11];
  const float* lin2_b  = (const float*)d_in[12];
  const float* ln_w    = (const float*)d_in[13];
  const float* ln_b    = (const float*)d_in[14];
  const float* GL      = (const float*)d_in[15];
  const float* GLlin_w = (const float*)d_in[16];
  const float* GLlin2_w= (const float*)d_in[17];
  float* out = (float*)d_out;

  ushort* U = (ushort*)d_ws;
  float* F = (float*)d_ws;
  const int M1U = 1048576;
  ushort* symP  = U + 0;            // 16M ushorts: E = exp(relu(sym))
  ushort* H0bf  = U + 16 * M1U;
  ushort* e2wbf = U + 17 * M1U;
  ushort* g1tbf = U + 18 * M1U;
  ushort* g2tbf = U + 19 * M1U;
  ushort* hTbf  = U + 20 * M1U;
  ushort* XAbf  = U + 21 * M1U;     // [b][e][n]
  ushort* XAT   = U + 22 * M1U;     // [b][n][e]
  ushort* g12T  = U + 23 * M1U;     // [n][k]
  ushort* gebf  = U + 24 * M1U;     // 2M
  ushort* y1b   = U + 26 * M1U;     // [b][e][n] bf16
  ushort* y2b   = U + 27 * M1U;
  ushort* w2bf  = U + 28 * M1U;     // 16K
  ushort* Acat  = U + 28 * M1U + 16384;
  ushort* glEbf = U + 28 * M1U + 32768;  // 64K
  // ushort region ends at 29,458,432 ushorts = 14,729,216 floats
  float* H02  = F + 14729216;
  float* SM   = F + 15777792;
  float* e1    = SM;
  float* e2    = SM + 16384;
  float* rsinv = SM + 32768;
  float* dd    = SM + 49152;   // 2048
  float* c1    = SM + 51200;
  float* c2    = SM + 52224;
  float* c12   = SM + 53248;
  float* lb2   = SM + 54272;   // 64 (pad)
  float* den   = SM + 54400;   // 16384
  float* part  = SM + 70784;   // 64

  // merged prep: lap rowsum | Acat/lb2/part0/glE/den0 | casts + embedding
  prep0_k<<<10658, 256, 0, stream>>>(
      graph, dd, lin1_w, lin2_w, lin2_b, lb2, Acat, GL, GLlin_w, glEbf,
      emb2_w, GLlin2_w, e2wbf, w2bf, x, emb_w, emb_b, H0bf, part, den);
  lap_fused_k<<<2048, 256, 0, stream>>>(graph, dd, g1tbf, g2tbf, c1, c2);
  lap_vec_k<<<1024, 256, 0, stream>>>(graph, dd, c1, c12, 1);

  // co-launched: H02 (z=0) || g12T (z=1)
  gg_k<<<dim3(16, 16, 2), 256, 0, stream>>>(
      H0bf, e2wbf, emb2_b, H02, g2tbf, g1tbf, g12T);

  // attention
  hmix_k<<<256, 256, 0, stream>>>(H02, att_W, att_a, hTbf, e1, e2);
  att_rowstats_k<<<Bn * Nn, 256, 0, stream>>>(e1, e2, rsinv);
  // xa = relu(P @ h) with split-K wave-groups + depth-2 pipeline
  pxa_k<<<dim3(16, 16), 512, 0, stream>>>(hTbf, e1, e2, rsinv, XAbf, XAT);

  // learned graph: ge = [XAT|glE] @ W2^T ; E = exp(relu(ge ge^T)) + den sums
  mgemm_k<4, 0, 1><<<dim3(16, 2, 16), 256, 0, stream>>>(
      XAT, w2bf, glEbf, gebf, nullptr,
      nullptr, nullptr, nullptr, nullptr,
      128, 64, 128, 128, PB, 0, (long)Nn * 128);
  mgemm_k<5, 0, 0><<<dim3(16, 16, 16), 256, 0, stream>>>(
      gebf, gebf, nullptr, symP, nullptr,
      nullptr, nullptr, nullptr, den,
      128, 128, 128, 1024, (long)Nn * 128, (long)Nn * 128, NNc);

  // fused u/w GEMMs + channel mixes + rank-1 + LN partials (split-K + depth-2)
  uwymix_k<<<dim3(16, 16), 512, 0, stream>>>(
      symP, den, g12T, XAbf, XAT, Acat, lin2_b, lb2, c2, c12,
      y1b, y2b, part);

  // fused final (LN finish + gelu + cell update)
  final_k<<<BEN / 256, 256, 0, stream>>>(y1b, y2b, XAbf, ct, ln_w, ln_b,
                                         part, out);
}